// Round 4
// baseline (709.952 us; speedup 1.0000x reference)
//
#include <hip/hip_runtime.h>
#include <hip/hip_bf16.h>
#include <math.h>

#define HW 4096
#define TP 264   // temporal A-tile pitch in halves: 528 B row stride == 4 mod 32 banks (2-way, free)

typedef __attribute__((ext_vector_type(8))) short bf16x8;
typedef _Float16 f16x8 __attribute__((ext_vector_type(8)));
typedef __attribute__((ext_vector_type(4))) float f32x4;

#define MFMA_BF16(a, b, c) __builtin_amdgcn_mfma_f32_16x16x32_bf16((a), (b), (c), 0, 0, 0)
#define MFMA_F16(a, b, c)  __builtin_amdgcn_mfma_f32_16x16x32_f16((a), (b), (c), 0, 0, 0)

static __device__ __forceinline__ float gelu_f(float xv) {
    // tanh-gelu via sigmoid identity: 0.5x(1+tanh(t)) = x*e/(e+1), e=exp(2t)
    float x2 = xv*xv;
    float t2 = xv*(1.5957691216057308f + 0.07135481627260025f*x2);
    float ee = __expf(t2);
    return xv*(1.f - __builtin_amdgcn_rcpf(ee + 1.f));
}

// ---------------- Prep: fp32 [nmat][128][128] -> bf16 [nmat][128][128] transposed ----------------
__global__ __launch_bounds__(256) void k_prep_t(
    const float* __restrict__ src, __hip_bfloat16* __restrict__ dst)
{
    __shared__ float t[32*33];
    int m  = blockIdx.x;
    int tr = blockIdx.y >> 2, tc = blockIdx.y & 3;
    int tid = threadIdx.x;
    for (int l = tid; l < 1024; l += 256) {
        int r = l >> 5, c = l & 31;
        t[r*33 + c] = src[m*16384 + (tr*32 + r)*128 + (tc*32 + c)];
    }
    __syncthreads();
    for (int l = tid; l < 1024; l += 256) {
        int c = l >> 5, r = l & 31;
        dst[m*16384 + (tc*32 + c)*128 + (tr*32 + r)] = __float2bfloat16(t[r*33 + c]);
    }
}

// ---------------- Prep: temporal tables + router weight tile ----------------
// Benc  f16 [128n][128k]: n<64 -> u_re col e: [Er[k][e] | -Ei[k-64][e]]
//                         n>=64 -> u_im col e: [Ei[k][e] |  Er[k-64][e]]
// BdecX f16 [64n][256k] : k and k+128 hold the SAME value (hi/lo split accumulation)
//                         base (k<128): [Dr[k][d] | -Di[k-64][d]]
// coefG float4[(b*16+t)*64+e] = (a_re, a_im, f_re, f_im);  nscG[b*16+t] = 0.01*sqrt(dt)
// rwB   bf16 [16n][128k]: n<4 -> router_w[k][n], rest zero (router as MFMA B-operand)
__global__ __launch_bounds__(256) void k_prep_enc(
    const float* __restrict__ encr, const float* __restrict__ enci,
    const float* __restrict__ decr, const float* __restrict__ deci,
    const float* __restrict__ dt,
    const float* __restrict__ lamr, const float* __restrict__ lami,
    const float* __restrict__ rw,
    _Float16* __restrict__ Benc, _Float16* __restrict__ BdecX,
    float4* __restrict__ coefG, float* __restrict__ nscG,
    __hip_bfloat16* __restrict__ rwB)
{
    int idx = blockIdx.x*256 + threadIdx.x;
    if (idx < 16384) {
        int n = idx >> 7, k = idx & 127;
        int e = n & 63, d = k & 63;
        float v;
        if (n < 64) v = (k < 64) ? encr[d*64 + e] : -enci[d*64 + e];
        else        v = (k < 64) ? enci[d*64 + e] :  encr[d*64 + e];
        Benc[idx] = (_Float16)v;
    }
    if (idx < 16384) {
        int n = idx >> 8, k = idx & 255;
        int kk = k & 127;
        int e = kk & 63;
        float v = (kk < 64) ? decr[e*64 + n] : -deci[e*64 + n];
        BdecX[idx] = (_Float16)v;
    }
    if (idx < 2048) {
        int bt = idx >> 6, e = idx & 63;
        float dtv = dt[bt];
        float lr = lamr[e];
        float sp = (lr > 20.f) ? lr : log1pf(expf(lr));
        float lre = -sp, lim = lami[e];
        float inv = 1.f / (lre*lre + lim*lim);
        float ex = expf(lre*dtv);
        float sn, cs; sincosf(lim*dtv, &sn, &cs);
        float ar = ex*cs, ai = ex*sn;
        float fr = ((ar - 1.f)*lre + ai*lim)*inv;
        float fi = (ai*lre - (ar - 1.f)*lim)*inv;
        coefG[idx] = make_float4(ar, ai, fr, fi);
    }
    if (idx < 2048) {
        int n = idx >> 7, k = idx & 127;
        float v = (n < 4) ? rw[k*4 + n] : 0.f;
        rwB[idx] = __float2bfloat16(v);
    }
    if (idx < 32) nscG[idx] = 0.01f * sqrtf(dt[idx]);
}

// ---------------- Stage 1a: spatial complex LayerNorm -> bf16 layout-A ----------------
__global__ __launch_bounds__(256) void k_ln_s(
    const float* __restrict__ xr, const float* __restrict__ xi,
    const float* __restrict__ lw, const float* __restrict__ lb,
    __hip_bfloat16* __restrict__ out)
{
    __shared__ float tile[64*129];
    __shared__ float ps[64*4];
    __shared__ float ps2[64*4];
    __shared__ float mu_s[64];
    __shared__ float rs_s[64];
    int bt  = blockIdx.x;
    int hw0 = blockIdx.y * 64;
    int tid = threadIdx.x;
    int wl = tid & 63;
    int q  = tid >> 6;
    float s = 0.f, s2 = 0.f;
    for (int c = q; c < 128; c += 4) {
        const float* src = (c < 64) ? xr : xi;
        int d = c & 63;
        float v = src[(bt*64 + d)*HW + hw0 + wl];
        tile[wl*129 + c] = v;
        s += v; s2 += v*v;
    }
    ps[wl*4 + q] = s;
    ps2[wl*4 + q] = s2;
    __syncthreads();
    if (tid < 64) {
        float ss = ps[tid*4+0]+ps[tid*4+1]+ps[tid*4+2]+ps[tid*4+3];
        float qq = ps2[tid*4+0]+ps2[tid*4+1]+ps2[tid*4+2]+ps2[tid*4+3];
        float mu = ss * 0.0078125f;
        float var = qq * 0.0078125f - mu*mu;
        mu_s[tid] = mu;
        rs_s[tid] = rsqrtf(var + 1e-5f);
    }
    __syncthreads();
    int c = tid & 127;
    int r = tid >> 7;
    float wc = lw[c], bc = lb[c];
    for (int wi = r; wi < 64; wi += 2) {
        float v = tile[wi*129 + c];
        out[(size_t)(bt*HW + hw0 + wi)*128 + c] =
            __float2bfloat16((v - mu_s[wi]) * rs_s[wi] * wc + bc);
    }
}

// ---------------- Stage 1b: 3x3 conv via MFMA implicit GEMM + bias + residual ----------------
__global__ __launch_bounds__(256) void k_conv_mfma(
    const __hip_bfloat16* __restrict__ xc,
    const __hip_bfloat16* __restrict__ wB,
    const float* __restrict__ cb,
    const float* __restrict__ xr, const float* __restrict__ xi,
    float* __restrict__ x1)
{
    __shared__ __align__(16) short inrow[3*66*136];
    int bt = blockIdx.x, h = blockIdx.y;
    int tid = threadIdx.x;
    if (tid < 96) {
        int r = tid / 32, t2 = tid & 31;
        int px = (t2 & 1) ? 65 : 0;
        int j = t2 >> 1;
        *(float4*)&inrow[(r*66 + px)*136 + j*8] = make_float4(0.f,0.f,0.f,0.f);
    }
    for (int c = tid; c < 3072; c += 256) {
        int r   = c >> 10;
        int rem = c & 1023;
        int px  = rem >> 4;
        int j   = rem & 15;
        int gh  = h + r - 1;
        float4 v = make_float4(0.f,0.f,0.f,0.f);
        if ((unsigned)gh < 64u)
            v = *(const float4*)&xc[(size_t)((bt*HW + gh*64 + px)*128) + j*8];
        *(float4*)&inrow[(r*66 + px + 1)*136 + j*8] = v;
    }
    __syncthreads();

    int wv = tid >> 6, l = tid & 63, lm = l & 15, q = l >> 4;
    int n0 = wv * 32;
    f32x4 acc[4][2];
    #pragma unroll
    for (int mi = 0; mi < 4; mi++)
        #pragma unroll
        for (int ni = 0; ni < 2; ni++)
            acc[mi][ni] = (f32x4){0.f,0.f,0.f,0.f};

    for (int p = 0; p < 9; p++) {
        int kh = p / 3, kw = p - kh*3;
        const __hip_bfloat16* wp = wB + p*16384;
        int abase = (kh*66 + kw)*136;
        #pragma unroll
        for (int ks = 0; ks < 4; ks++) {
            int ko = ks*32 + q*8;
            bf16x8 b0 = *(const bf16x8*)(wp + (n0 + lm)*128 + ko);
            bf16x8 b1 = *(const bf16x8*)(wp + (n0 + 16 + lm)*128 + ko);
            #pragma unroll
            for (int mi = 0; mi < 4; mi++) {
                bf16x8 a = *(const bf16x8*)&inrow[abase + (mi*16 + lm)*136 + ko];
                acc[mi][0] = MFMA_BF16(a, b0, acc[mi][0]);
                acc[mi][1] = MFMA_BF16(a, b1, acc[mi][1]);
            }
        }
    }
    #pragma unroll
    for (int ni = 0; ni < 2; ni++) {
        int oc = n0 + ni*16 + lm;
        float bias = cb[oc];
        const float* rsp = (oc < 64) ? xr : xi;
        const float* rbase = &rsp[(bt*64 + (oc & 63))*HW + h*64];
        #pragma unroll
        for (int mi = 0; mi < 4; mi++) {
            #pragma unroll
            for (int r = 0; r < 4; r++) {
                int w = mi*16 + q*4 + r;
                x1[(size_t)(bt*HW + h*64 + w)*128 + oc] = acc[mi][ni][r] + bias + rbase[w];
            }
        }
    }
}

// ---------------- Stage 2: temporal via MFMA, f16 + hi/lo-split decode ----------------
// block = 128 thr / 2 waves, 4 pixels. A-tile 64 rows = (n_local,t), pitch 264:
// cols 0..127 = z then h_hi [re|im]; cols 128..255 = h_lo [re|im].
// GEMM1 (encode, K=128) -> in-fragment complex scan -> h hi/lo to tile -> GEMM2 (decode, K=256).
__global__ __launch_bounds__(128) void k_temporal_mfma(
    float* xio,
    const float* __restrict__ lw, const float* __restrict__ lb,
    const float* __restrict__ sbr, const float* __restrict__ sbi,
    const _Float16* __restrict__ Benc, const _Float16* __restrict__ BdecX,
    const float4* __restrict__ coefG, const float* __restrict__ nscG,
    const float* __restrict__ nzr, const float* __restrict__ nzi)
{
    __shared__ __align__(16) short At[64*TP];   // 33792 B
    int n0  = blockIdx.x * 4;
    int b   = n0 >> 12;
    int hw0 = n0 & 4095;
    int tid = threadIdx.x;

    // LN: 2 threads per row (row = n_local*16 + t), f16 into A-tile cols 0..127
    {
        int row = tid >> 1, half = tid & 1;
        int nl = row >> 4, t = row & 15;
        const float4* src = (const float4*)&xio[((size_t)((b*16 + t)*HW) + hw0 + nl)*128 + half*64];
        float4 v[16];
        float s = 0.f, s2 = 0.f;
        #pragma unroll
        for (int j = 0; j < 16; j++) {
            v[j] = src[j];
            s  += v[j].x + v[j].y + v[j].z + v[j].w;
            s2 += v[j].x*v[j].x + v[j].y*v[j].y + v[j].z*v[j].z + v[j].w*v[j].w;
        }
        s  += __shfl_xor(s, 1, 64);
        s2 += __shfl_xor(s2, 1, 64);
        float mu  = s * 0.0078125f;
        float var = s2 * 0.0078125f - mu*mu;
        float rsq = rsqrtf(var + 1e-5f);
        const float4* lw4 = (const float4*)(lw + half*64);
        const float4* lb4 = (const float4*)(lb + half*64);
        short* dstrow = &At[row*TP + half*64];
        #pragma unroll
        for (int j = 0; j < 16; j++) {
            float4 wv4 = lw4[j], bv = lb4[j];
            union { _Float16 h[4]; float2 f; } u;
            u.h[0] = (_Float16)((v[j].x - mu)*rsq*wv4.x + bv.x);
            u.h[1] = (_Float16)((v[j].y - mu)*rsq*wv4.y + bv.y);
            u.h[2] = (_Float16)((v[j].z - mu)*rsq*wv4.z + bv.z);
            u.h[3] = (_Float16)((v[j].w - mu)*rsq*wv4.w + bv.w);
            *(float2*)(dstrow + j*4) = u.f;
        }
    }
    __syncthreads();   // coef/LN cross-wave publish; tile rows are wave-private below

    int wv = tid >> 6, l = tid & 63, lm = l & 15, q = l >> 4;

    // GEMM1: u_pre = z @ Benc  (ni<4 = re cols, ni+4 = im cols)
    f32x4 acc[2][8];
    #pragma unroll
    for (int mi = 0; mi < 2; mi++)
        #pragma unroll
        for (int ni = 0; ni < 8; ni++)
            acc[mi][ni] = (f32x4){0.f,0.f,0.f,0.f};
    #pragma unroll
    for (int ks = 0; ks < 4; ks++) {
        int ko = ks*32 + q*8;
        f16x8 a0 = *(const f16x8*)&At[((2*wv+0)*16 + lm)*TP + ko];
        f16x8 a1 = *(const f16x8*)&At[((2*wv+1)*16 + lm)*TP + ko];
        #pragma unroll
        for (int ni = 0; ni < 8; ni++) {
            f16x8 bb = *(const f16x8*)(Benc + (ni*16 + lm)*128 + ko);
            acc[0][ni] = MFMA_F16(a0, bb, acc[0][ni]);
            acc[1][ni] = MFMA_F16(a1, bb, acc[1][ni]);
        }
    }

    // in-fragment complex scan (coef from global table); write h hi/lo into wave rows
    int btbase = b*16;
    #pragma unroll
    for (int ni = 0; ni < 4; ni++) {
        int e = ni*16 + lm;
        float br = sbr[e], bi = sbi[e];
        float4 cf[4]; float ns[4];
        #pragma unroll
        for (int r = 0; r < 4; r++) {
            int t = q*4 + r;
            cf[r] = coefG[(btbase + t)*64 + e];
            ns[r] = nscG[btbase + t];
        }
        #pragma unroll
        for (int mi = 0; mi < 2; mi++) {
            int nl = 2*wv + mi;
            int ng = n0 + nl;
            float nrv[4], niv[4];
            #pragma unroll
            for (int r = 0; r < 4; r++) {
                int off = (ng*16 + q*4 + r)*64 + e;
                nrv[r] = nzr[off];
                niv[r] = nzi[off];
            }
            float hr = 0.f, hi = 0.f, Apr = 1.f, Api = 0.f;
            float hrs[4], his[4], Aprs[4], Apis[4];
            #pragma unroll
            for (int r = 0; r < 4; r++) {
                float Sr = acc[mi][ni][r] + br;
                float Si = acc[mi][ni+4][r] + bi;
                float ur = Sr*cf[r].z - Si*cf[r].w + ns[r]*nrv[r];
                float ui = Sr*cf[r].w + Si*cf[r].z + ns[r]*niv[r];
                if (r == 0) { hr = ur; hi = ui; Apr = cf[0].x; Api = cf[0].y; }
                else {
                    float tr = cf[r].x*hr - cf[r].y*hi + ur;
                    float ti = cf[r].x*hi + cf[r].y*hr + ui;
                    hr = tr; hi = ti;
                    tr = cf[r].x*Apr - cf[r].y*Api;
                    ti = cf[r].x*Api + cf[r].y*Apr;
                    Apr = tr; Api = ti;
                }
                hrs[r] = hr; his[r] = hi; Aprs[r] = Apr; Apis[r] = Api;
            }
            // quad-prefix over segments (A,H): h_out = H + A*h_in
            float Ar = Apr, Ai = Api, Hr = hr, Hi = hi;
            #pragma unroll
            for (int off = 16; off <= 32; off <<= 1) {
                float pAr = __shfl_up(Ar, off, 64);
                float pAi = __shfl_up(Ai, off, 64);
                float pHr = __shfl_up(Hr, off, 64);
                float pHi = __shfl_up(Hi, off, 64);
                if (l >= off) {
                    Hr = Hr + Ar*pHr - Ai*pHi;
                    Hi = Hi + Ar*pHi + Ai*pHr;
                    float tAr = Ar*pAr - Ai*pAi;
                    float tAi = Ar*pAi + Ai*pAr;
                    Ar = tAr; Ai = tAi;
                }
            }
            float gr = __shfl_up(Hr, 16, 64);
            float gi = __shfl_up(Hi, 16, 64);
            if (q == 0) { gr = 0.f; gi = 0.f; }
            #pragma unroll
            for (int r = 0; r < 4; r++) {
                float fhr = hrs[r] + Aprs[r]*gr - Apis[r]*gi;
                float fhi = his[r] + Aprs[r]*gi + Apis[r]*gr;
                int row = nl*16 + q*4 + r;
                _Float16 hrh = (_Float16)fhr;
                _Float16 hih = (_Float16)fhi;
                *(_Float16*)&At[row*TP + e]        = hrh;
                *(_Float16*)&At[row*TP + 64 + e]   = hih;
                *(_Float16*)&At[row*TP + 128 + e]  = (_Float16)(fhr - (float)hrh);
                *(_Float16*)&At[row*TP + 192 + e]  = (_Float16)(fhi - (float)hih);
            }
        }
    }

    // GEMM2: drift = (h_hi + h_lo) @ BdecX  (K=256, duplicated weights)
    f32x4 acc2[2][4];
    #pragma unroll
    for (int mi = 0; mi < 2; mi++)
        #pragma unroll
        for (int ni = 0; ni < 4; ni++)
            acc2[mi][ni] = (f32x4){0.f,0.f,0.f,0.f};
    #pragma unroll
    for (int ks = 0; ks < 8; ks++) {
        int ko = ks*32 + q*8;
        f16x8 a0 = *(const f16x8*)&At[((2*wv+0)*16 + lm)*TP + ko];
        f16x8 a1 = *(const f16x8*)&At[((2*wv+1)*16 + lm)*TP + ko];
        #pragma unroll
        for (int ni = 0; ni < 4; ni++) {
            f16x8 bb = *(const f16x8*)(BdecX + (ni*16 + lm)*256 + ko);
            acc2[0][ni] = MFMA_F16(a0, bb, acc2[0][ni]);
            acc2[1][ni] = MFMA_F16(a1, bb, acc2[1][ni]);
        }
    }

    // epilogue: xio.re += drift (in place, re-half only)
    #pragma unroll
    for (int mi = 0; mi < 2; mi++) {
        int nl = 2*wv + mi;
        #pragma unroll
        for (int ni = 0; ni < 4; ni++) {
            int d = ni*16 + lm;
            #pragma unroll
            for (int r = 0; r < 4; r++) {
                int t = q*4 + r;
                size_t idx = ((size_t)((b*16 + t)*HW) + hw0 + nl)*128 + d;
                xio[idx] = xio[idx] + acc2[mi][ni][r];
            }
        }
    }
}

// ---------------- Stage 3: MoE FFN via MFMA; wave-private row blocks, barrier-free experts ----
// Each wave owns token rows [wv*16, wv*16+16). GEMM1 produces hid[own rows][all 128 cols],
// GELU writes only own rows, GEMM2 reads only own rows (A-frag row index = lm stays inside
// the 16-row block), gates written/read for own rows only. All hid/gates dependencies are
// wave-private -> per-wave in-order DS suffices (same trick as k_temporal's At tile), so the
// expert loop has ZERO barriers. Barriers: stage(1) + pre-tile-reuse(1) + pre-store(1) = 3.
__global__ __launch_bounds__(256) void k_moe_mfma(
    const float* __restrict__ xio,
    float* __restrict__ outp,
    const __hip_bfloat16* __restrict__ rwB, const float* __restrict__ rb,
    const __hip_bfloat16* __restrict__ w1b, const float* __restrict__ b1,
    const __hip_bfloat16* __restrict__ w2b, const float* __restrict__ b2)
{
    __shared__ __align__(16) short smem[2*64*136];   // tokA | hidA; reused as fp32 tile 64x129
    __shared__ float gates[256];
    short* tokA = smem;
    short* hidA = smem + 64*136;
    float* tile = (float*)smem;
    int tok0 = blockIdx.x * 64;
    int tid = threadIdx.x;
    for (int lsd = tid; lsd < 2048; lsd += 256) {
        int t = lsd >> 5, j = lsd & 31;
        float4 v = *(const float4*)&xio[(size_t)(tok0 + t)*128 + j*4];
        union { __hip_bfloat16 h[4]; float2 f; } u;
        u.h[0] = __float2bfloat16(v.x);
        u.h[1] = __float2bfloat16(v.y);
        u.h[2] = __float2bfloat16(v.z);
        u.h[3] = __float2bfloat16(v.w);
        *(float2*)&tokA[t*136 + j*4] = u.f;
    }
    __syncthreads();

    int wv = tid >> 6, l = tid & 63, lm = l & 15, q = l >> 4;
    int r0 = wv * 16;        // this wave's private token-row block

    // Router via MFMA for own 16 rows; gates stored per-row (wave-private rows).
    {
        f32x4 racc = (f32x4){0.f,0.f,0.f,0.f};
        #pragma unroll
        for (int ks = 0; ks < 4; ks++) {
            int ko = ks*32 + q*8;
            bf16x8 bb = *(const bf16x8*)(rwB + lm*128 + ko);
            bf16x8 a  = *(const bf16x8*)&tokA[(r0 + lm)*136 + ko];
            racc = MFMA_BF16(a, bb, racc);
        }
        float rb_l = rb[lm & 3];
        #pragma unroll
        for (int r = 0; r < 4; r++) {
            float g = racc[r] + rb_l;
            // softmax over experts: lanes lm=0..3 within aligned 4-lane groups
            float mx = fmaxf(g, __shfl_xor(g, 1, 64));
            mx = fmaxf(mx, __shfl_xor(mx, 2, 64));
            float ev = __expf(g - mx);
            float sv = ev + __shfl_xor(ev, 1, 64);
            sv += __shfl_xor(sv, 2, 64);
            if (lm < 4)
                gates[(r0 + q*4 + r)*4 + lm] = ev * __builtin_amdgcn_rcpf(sv);
        }
    }

    f32x4 outa[8];
    #pragma unroll
    for (int ni = 0; ni < 8; ni++)
        outa[ni] = (f32x4){0.f,0.f,0.f,0.f};

    // Barrier-free expert loop: all hid/gates traffic stays in this wave's row block.
    #pragma unroll
    for (int e = 0; e < 4; e++) {
        // GEMM1: hid[own rows][0..127] = tok[own rows] @ w1[e]
        f32x4 acc1[8];
        #pragma unroll
        for (int ni = 0; ni < 8; ni++)
            acc1[ni] = (f32x4){0.f,0.f,0.f,0.f};
        const __hip_bfloat16* wp1 = w1b + e*16384;
        #pragma unroll
        for (int ks = 0; ks < 4; ks++) {
            int ko = ks*32 + q*8;
            bf16x8 a = *(const bf16x8*)&tokA[(r0 + lm)*136 + ko];
            #pragma unroll
            for (int ni = 0; ni < 8; ni++) {
                bf16x8 bb = *(const bf16x8*)(wp1 + (ni*16 + lm)*128 + ko);
                acc1[ni] = MFMA_BF16(a, bb, acc1[ni]);
            }
        }
        // GELU -> hid own rows (u16 writes merge per dword; pitch-136 keeps ~2-way)
        #pragma unroll
        for (int ni = 0; ni < 8; ni++) {
            int hcol = ni*16 + lm;
            float bb = b1[e*128 + hcol];
            #pragma unroll
            for (int r = 0; r < 4; r++) {
                float hv = gelu_f(acc1[ni][r] + bb);
                int m = r0 + q*4 + r;
                *(__hip_bfloat16*)&hidA[m*136 + hcol] = __float2bfloat16(hv);
            }
        }
        // GEMM2: delta[own rows][0..127] = hid[own rows] @ w2[e]   (wave-private RAW on hidA)
        f32x4 acc2[8];
        #pragma unroll
        for (int ni = 0; ni < 8; ni++)
            acc2[ni] = (f32x4){0.f,0.f,0.f,0.f};
        const __hip_bfloat16* wp2 = w2b + e*16384;
        #pragma unroll
        for (int ks = 0; ks < 4; ks++) {
            int ko = ks*32 + q*8;
            bf16x8 a = *(const bf16x8*)&hidA[(r0 + lm)*136 + ko];
            #pragma unroll
            for (int ni = 0; ni < 8; ni++) {
                bf16x8 bb = *(const bf16x8*)(wp2 + (ni*16 + lm)*128 + ko);
                acc2[ni] = MFMA_BF16(a, bb, acc2[ni]);
            }
        }
        // gate/bias fold (gates rows are wave-private)
        float g4[4];
        #pragma unroll
        for (int r = 0; r < 4; r++)
            g4[r] = gates[(r0 + q*4 + r)*4 + e];
        #pragma unroll
        for (int ni = 0; ni < 8; ni++) {
            float bb = b2[e*128 + ni*16 + lm];
            #pragma unroll
            for (int r = 0; r < 4; r++)
                outa[ni][r] += g4[r] * (acc2[ni][r] + bb);
        }
    }
    __syncthreads();   // everyone done with tokA/hidA; reuse as fp32 tile

    // final = residual + delta -> LDS tile (pitch 129), own rows only
    #pragma unroll
    for (int ni = 0; ni < 8; ni++) {
        int col = ni*16 + lm;
        #pragma unroll
        for (int r = 0; r < 4; r++) {
            int m = r0 + q*4 + r;
            tile[m*129 + col] = xio[(size_t)(tok0 + m)*128 + col] + outa[ni][r];
        }
    }
    __syncthreads();
    int bt = tok0 >> 12;
    int hw0 = tok0 & 4095;
    for (int lid = tid; lid < 8192; lid += 256) {
        int c = lid >> 6, m = lid & 63;
        int p = c >> 6, d = c & 63;
        outp[((size_t)((p*32 + bt)*64 + d))*HW + hw0 + m] = tile[m*129 + c];
    }
}

extern "C" void kernel_launch(void* const* d_in, const int* in_sizes, int n_in,
                              void* d_out, int out_size, void* d_ws, size_t ws_size,
                              hipStream_t stream)
{
    const float* x_real = (const float*)d_in[0];
    const float* x_imag = (const float*)d_in[1];
    const float* dt     = (const float*)d_in[2];
    const float* nzr    = (const float*)d_in[3];
    const float* nzi    = (const float*)d_in[4];
    const float* ln_s_w = (const float*)d_in[5];
    const float* ln_s_b = (const float*)d_in[6];
    const float* conv_w = (const float*)d_in[7];
    const float* conv_b = (const float*)d_in[8];
    const float* ln_t_w = (const float*)d_in[9];
    const float* ln_t_b = (const float*)d_in[10];
    const float* lam_re = (const float*)d_in[11];
    const float* lam_im = (const float*)d_in[12];
    const float* sbr    = (const float*)d_in[13];
    const float* sbi    = (const float*)d_in[14];
    const float* enc_re = (const float*)d_in[15];
    const float* enc_im = (const float*)d_in[16];
    const float* dec_re = (const float*)d_in[17];
    const float* dec_im = (const float*)d_in[18];
    const float* rw     = (const float*)d_in[19];
    const float* rb     = (const float*)d_in[20];
    const float* w1     = (const float*)d_in[21];
    const float* b1     = (const float*)d_in[22];
    const float* w2     = (const float*)d_in[23];
    const float* b2     = (const float*)d_in[24];

    char* ws = (char*)d_ws;
    float* bufA = (float*)ws;                                              // 64 MiB fp32 layout-A
    __hip_bfloat16* bufB = (__hip_bfloat16*)(ws + (size_t)64*1024*1024);   // 32 MiB bf16 (ln_s -> conv)
    __hip_bfloat16* wBc  = (__hip_bfloat16*)(ws + (size_t)96*1024*1024);   // conv weights [9][oc][ic]
    __hip_bfloat16* w1b  = wBc + 9*16384;
    __hip_bfloat16* w2b  = w1b + 4*16384;
    _Float16* Benc  = (_Float16*)(w2b + 4*16384);                          // [128][128] f16
    _Float16* BdecX = Benc + 16384;                                        // [64][256] f16
    float4* coefG = (float4*)(BdecX + 16384);                              // [2048]
    float* nscG   = (float*)(coefG + 2048);                                // [32]
    __hip_bfloat16* rwB = (__hip_bfloat16*)(nscG + 32);                    // [16][128] bf16 router
    float* outp = (float*)d_out;

    k_prep_t  <<<dim3(9,16), 256, 0, stream>>>(conv_w, wBc);
    k_prep_t  <<<dim3(4,16), 256, 0, stream>>>(w1, w1b);
    k_prep_t  <<<dim3(4,16), 256, 0, stream>>>(w2, w2b);
    k_prep_enc<<<64,         256, 0, stream>>>(enc_re, enc_im, dec_re, dec_im,
                                               dt, lam_re, lam_im, rw,
                                               Benc, BdecX, coefG, nscG, rwB);

    k_ln_s         <<<dim3(32,64), 256, 0, stream>>>(x_real, x_imag, ln_s_w, ln_s_b, bufB);
    k_conv_mfma    <<<dim3(32,64), 256, 0, stream>>>(bufB, wBc, conv_b, x_real, x_imag, bufA);
    k_temporal_mfma<<<2048,        128, 0, stream>>>(bufA, ln_t_w, ln_t_b, sbr, sbi,
                                                     Benc, BdecX, coefG, nscG, nzr, nzi);
    k_moe_mfma     <<<2048,        256, 0, stream>>>(bufA, outp, rwB, rb, w1b, b1, w2b, b2);
}

// Round 8
// 611.443 us; speedup vs baseline: 1.1611x; 1.1611x over previous
//
#include <hip/hip_runtime.h>
#include <hip/hip_bf16.h>
#include <math.h>

#define HW 4096
#define TP 264   // temporal A-tile pitch in halves: 528 B row stride == 4 mod 32 banks (2-way, free)

typedef __attribute__((ext_vector_type(8))) short bf16x8;
typedef _Float16 f16x8 __attribute__((ext_vector_type(8)));
typedef __attribute__((ext_vector_type(4))) float f32x4;

#define MFMA_BF16(a, b, c) __builtin_amdgcn_mfma_f32_16x16x32_bf16((a), (b), (c), 0, 0, 0)
#define MFMA_F16(a, b, c)  __builtin_amdgcn_mfma_f32_16x16x32_f16((a), (b), (c), 0, 0, 0)

static __device__ __forceinline__ float gelu_f(float xv) {
    // tanh-gelu via sigmoid identity: 0.5x(1+tanh(t)) = x*e/(e+1), e=exp(2t)
    float x2 = xv*xv;
    float t2 = xv*(1.5957691216057308f + 0.07135481627260025f*x2);
    float ee = __expf(t2);
    return xv*(1.f - __builtin_amdgcn_rcpf(ee + 1.f));
}

// ---------------- Prep: fp32 [nmat][128][128] -> bf16 [nmat][128][128] transposed ----------------
__global__ __launch_bounds__(256) void k_prep_t(
    const float* __restrict__ src, __hip_bfloat16* __restrict__ dst)
{
    __shared__ float t[32*33];
    int m  = blockIdx.x;
    int tr = blockIdx.y >> 2, tc = blockIdx.y & 3;
    int tid = threadIdx.x;
    for (int l = tid; l < 1024; l += 256) {
        int r = l >> 5, c = l & 31;
        t[r*33 + c] = src[m*16384 + (tr*32 + r)*128 + (tc*32 + c)];
    }
    __syncthreads();
    for (int l = tid; l < 1024; l += 256) {
        int c = l >> 5, r = l & 31;
        dst[m*16384 + (tc*32 + c)*128 + (tr*32 + r)] = __float2bfloat16(t[r*33 + c]);
    }
}

// ---------------- Prep: temporal tables + router weight tile ----------------
// Benc  f16 [128n][128k]: n<64 -> u_re col e: [Er[k][e] | -Ei[k-64][e]]
//                         n>=64 -> u_im col e: [Ei[k][e] |  Er[k-64][e]]
// BdecX f16 [64n][256k] : k and k+128 hold the SAME value (hi/lo split accumulation)
//                         base (k<128): [Dr[k][d] | -Di[k-64][d]]
// coefG float4[(b*16+t)*64+e] = (a_re, a_im, f_re, f_im);  nscG[b*16+t] = 0.01*sqrt(dt)
// rwB   bf16 [16n][128k]: n<4 -> router_w[k][n], rest zero (router as MFMA B-operand)
__global__ __launch_bounds__(256) void k_prep_enc(
    const float* __restrict__ encr, const float* __restrict__ enci,
    const float* __restrict__ decr, const float* __restrict__ deci,
    const float* __restrict__ dt,
    const float* __restrict__ lamr, const float* __restrict__ lami,
    const float* __restrict__ rw,
    _Float16* __restrict__ Benc, _Float16* __restrict__ BdecX,
    float4* __restrict__ coefG, float* __restrict__ nscG,
    __hip_bfloat16* __restrict__ rwB)
{
    int idx = blockIdx.x*256 + threadIdx.x;
    if (idx < 16384) {
        int n = idx >> 7, k = idx & 127;
        int e = n & 63, d = k & 63;
        float v;
        if (n < 64) v = (k < 64) ? encr[d*64 + e] : -enci[d*64 + e];
        else        v = (k < 64) ? enci[d*64 + e] :  encr[d*64 + e];
        Benc[idx] = (_Float16)v;
    }
    if (idx < 16384) {
        int n = idx >> 8, k = idx & 255;
        int kk = k & 127;
        int e = kk & 63;
        float v = (kk < 64) ? decr[e*64 + n] : -deci[e*64 + n];
        BdecX[idx] = (_Float16)v;
    }
    if (idx < 2048) {
        int bt = idx >> 6, e = idx & 63;
        float dtv = dt[bt];
        float lr = lamr[e];
        float sp = (lr > 20.f) ? lr : log1pf(expf(lr));
        float lre = -sp, lim = lami[e];
        float inv = 1.f / (lre*lre + lim*lim);
        float ex = expf(lre*dtv);
        float sn, cs; sincosf(lim*dtv, &sn, &cs);
        float ar = ex*cs, ai = ex*sn;
        float fr = ((ar - 1.f)*lre + ai*lim)*inv;
        float fi = (ai*lre - (ar - 1.f)*lim)*inv;
        coefG[idx] = make_float4(ar, ai, fr, fi);
    }
    if (idx < 2048) {
        int n = idx >> 7, k = idx & 127;
        float v = (n < 4) ? rw[k*4 + n] : 0.f;
        rwB[idx] = __float2bfloat16(v);
    }
    if (idx < 32) nscG[idx] = 0.01f * sqrtf(dt[idx]);
}

// ---------------- Stage 1a: spatial complex LayerNorm -> bf16 layout-A ----------------
__global__ __launch_bounds__(256) void k_ln_s(
    const float* __restrict__ xr, const float* __restrict__ xi,
    const float* __restrict__ lw, const float* __restrict__ lb,
    __hip_bfloat16* __restrict__ out)
{
    __shared__ float tile[64*129];
    __shared__ float ps[64*4];
    __shared__ float ps2[64*4];
    __shared__ float mu_s[64];
    __shared__ float rs_s[64];
    int bt  = blockIdx.x;
    int hw0 = blockIdx.y * 64;
    int tid = threadIdx.x;
    int wl = tid & 63;
    int q  = tid >> 6;
    float s = 0.f, s2 = 0.f;
    for (int c = q; c < 128; c += 4) {
        const float* src = (c < 64) ? xr : xi;
        int d = c & 63;
        float v = src[(bt*64 + d)*HW + hw0 + wl];
        tile[wl*129 + c] = v;
        s += v; s2 += v*v;
    }
    ps[wl*4 + q] = s;
    ps2[wl*4 + q] = s2;
    __syncthreads();
    if (tid < 64) {
        float ss = ps[tid*4+0]+ps[tid*4+1]+ps[tid*4+2]+ps[tid*4+3];
        float qq = ps2[tid*4+0]+ps2[tid*4+1]+ps2[tid*4+2]+ps2[tid*4+3];
        float mu = ss * 0.0078125f;
        float var = qq * 0.0078125f - mu*mu;
        mu_s[tid] = mu;
        rs_s[tid] = rsqrtf(var + 1e-5f);
    }
    __syncthreads();
    int c = tid & 127;
    int r = tid >> 7;
    float wc = lw[c], bc = lb[c];
    for (int wi = r; wi < 64; wi += 2) {
        float v = tile[wi*129 + c];
        out[(size_t)(bt*HW + hw0 + wi)*128 + c] =
            __float2bfloat16((v - mu_s[wi]) * rs_s[wi] * wc + bc);
    }
}

// ---------------- Stage 1b: 3x3 conv via MFMA implicit GEMM + bias + residual ----------------
__global__ __launch_bounds__(256) void k_conv_mfma(
    const __hip_bfloat16* __restrict__ xc,
    const __hip_bfloat16* __restrict__ wB,
    const float* __restrict__ cb,
    const float* __restrict__ xr, const float* __restrict__ xi,
    float* __restrict__ x1)
{
    __shared__ __align__(16) short inrow[3*66*136];
    int bt = blockIdx.x, h = blockIdx.y;
    int tid = threadIdx.x;
    if (tid < 96) {
        int r = tid / 32, t2 = tid & 31;
        int px = (t2 & 1) ? 65 : 0;
        int j = t2 >> 1;
        *(float4*)&inrow[(r*66 + px)*136 + j*8] = make_float4(0.f,0.f,0.f,0.f);
    }
    for (int c = tid; c < 3072; c += 256) {
        int r   = c >> 10;
        int rem = c & 1023;
        int px  = rem >> 4;
        int j   = rem & 15;
        int gh  = h + r - 1;
        float4 v = make_float4(0.f,0.f,0.f,0.f);
        if ((unsigned)gh < 64u)
            v = *(const float4*)&xc[(size_t)((bt*HW + gh*64 + px)*128) + j*8];
        *(float4*)&inrow[(r*66 + px + 1)*136 + j*8] = v;
    }
    __syncthreads();

    int wv = tid >> 6, l = tid & 63, lm = l & 15, q = l >> 4;
    int n0 = wv * 32;
    f32x4 acc[4][2];
    #pragma unroll
    for (int mi = 0; mi < 4; mi++)
        #pragma unroll
        for (int ni = 0; ni < 2; ni++)
            acc[mi][ni] = (f32x4){0.f,0.f,0.f,0.f};

    for (int p = 0; p < 9; p++) {
        int kh = p / 3, kw = p - kh*3;
        const __hip_bfloat16* wp = wB + p*16384;
        int abase = (kh*66 + kw)*136;
        #pragma unroll
        for (int ks = 0; ks < 4; ks++) {
            int ko = ks*32 + q*8;
            bf16x8 b0 = *(const bf16x8*)(wp + (n0 + lm)*128 + ko);
            bf16x8 b1 = *(const bf16x8*)(wp + (n0 + 16 + lm)*128 + ko);
            #pragma unroll
            for (int mi = 0; mi < 4; mi++) {
                bf16x8 a = *(const bf16x8*)&inrow[abase + (mi*16 + lm)*136 + ko];
                acc[mi][0] = MFMA_BF16(a, b0, acc[mi][0]);
                acc[mi][1] = MFMA_BF16(a, b1, acc[mi][1]);
            }
        }
    }
    #pragma unroll
    for (int ni = 0; ni < 2; ni++) {
        int oc = n0 + ni*16 + lm;
        float bias = cb[oc];
        const float* rsp = (oc < 64) ? xr : xi;
        const float* rbase = &rsp[(bt*64 + (oc & 63))*HW + h*64];
        #pragma unroll
        for (int mi = 0; mi < 4; mi++) {
            #pragma unroll
            for (int r = 0; r < 4; r++) {
                int w = mi*16 + q*4 + r;
                x1[(size_t)(bt*HW + h*64 + w)*128 + oc] = acc[mi][ni][r] + bias + rbase[w];
            }
        }
    }
}

// ---------------- Stage 2: temporal via MFMA, f16 + hi/lo-split decode ----------------
// block = 128 thr / 2 waves, 4 pixels. A-tile 64 rows = (n_local,t), pitch 264:
// cols 0..127 = z then h_hi [re|im]; cols 128..255 = h_lo [re|im].
// GEMM1 (encode, K=128) -> in-fragment complex scan -> h hi/lo to tile -> GEMM2 (decode, K=256).
__global__ __launch_bounds__(128) void k_temporal_mfma(
    float* xio,
    const float* __restrict__ lw, const float* __restrict__ lb,
    const float* __restrict__ sbr, const float* __restrict__ sbi,
    const _Float16* __restrict__ Benc, const _Float16* __restrict__ BdecX,
    const float4* __restrict__ coefG, const float* __restrict__ nscG,
    const float* __restrict__ nzr, const float* __restrict__ nzi)
{
    __shared__ __align__(16) short At[64*TP];   // 33792 B
    int n0  = blockIdx.x * 4;
    int b   = n0 >> 12;
    int hw0 = n0 & 4095;
    int tid = threadIdx.x;

    // LN: 2 threads per row (row = n_local*16 + t), f16 into A-tile cols 0..127
    {
        int row = tid >> 1, half = tid & 1;
        int nl = row >> 4, t = row & 15;
        const float4* src = (const float4*)&xio[((size_t)((b*16 + t)*HW) + hw0 + nl)*128 + half*64];
        float4 v[16];
        float s = 0.f, s2 = 0.f;
        #pragma unroll
        for (int j = 0; j < 16; j++) {
            v[j] = src[j];
            s  += v[j].x + v[j].y + v[j].z + v[j].w;
            s2 += v[j].x*v[j].x + v[j].y*v[j].y + v[j].z*v[j].z + v[j].w*v[j].w;
        }
        s  += __shfl_xor(s, 1, 64);
        s2 += __shfl_xor(s2, 1, 64);
        float mu  = s * 0.0078125f;
        float var = s2 * 0.0078125f - mu*mu;
        float rsq = rsqrtf(var + 1e-5f);
        const float4* lw4 = (const float4*)(lw + half*64);
        const float4* lb4 = (const float4*)(lb + half*64);
        short* dstrow = &At[row*TP + half*64];
        #pragma unroll
        for (int j = 0; j < 16; j++) {
            float4 wv4 = lw4[j], bv = lb4[j];
            union { _Float16 h[4]; float2 f; } u;
            u.h[0] = (_Float16)((v[j].x - mu)*rsq*wv4.x + bv.x);
            u.h[1] = (_Float16)((v[j].y - mu)*rsq*wv4.y + bv.y);
            u.h[2] = (_Float16)((v[j].z - mu)*rsq*wv4.z + bv.z);
            u.h[3] = (_Float16)((v[j].w - mu)*rsq*wv4.w + bv.w);
            *(float2*)(dstrow + j*4) = u.f;
        }
    }
    __syncthreads();   // coef/LN cross-wave publish; tile rows are wave-private below

    int wv = tid >> 6, l = tid & 63, lm = l & 15, q = l >> 4;

    // GEMM1: u_pre = z @ Benc  (ni<4 = re cols, ni+4 = im cols)
    f32x4 acc[2][8];
    #pragma unroll
    for (int mi = 0; mi < 2; mi++)
        #pragma unroll
        for (int ni = 0; ni < 8; ni++)
            acc[mi][ni] = (f32x4){0.f,0.f,0.f,0.f};
    #pragma unroll
    for (int ks = 0; ks < 4; ks++) {
        int ko = ks*32 + q*8;
        f16x8 a0 = *(const f16x8*)&At[((2*wv+0)*16 + lm)*TP + ko];
        f16x8 a1 = *(const f16x8*)&At[((2*wv+1)*16 + lm)*TP + ko];
        #pragma unroll
        for (int ni = 0; ni < 8; ni++) {
            f16x8 bb = *(const f16x8*)(Benc + (ni*16 + lm)*128 + ko);
            acc[0][ni] = MFMA_F16(a0, bb, acc[0][ni]);
            acc[1][ni] = MFMA_F16(a1, bb, acc[1][ni]);
        }
    }

    // in-fragment complex scan (coef from global table); write h hi/lo into wave rows
    int btbase = b*16;
    #pragma unroll
    for (int ni = 0; ni < 4; ni++) {
        int e = ni*16 + lm;
        float br = sbr[e], bi = sbi[e];
        float4 cf[4]; float ns[4];
        #pragma unroll
        for (int r = 0; r < 4; r++) {
            int t = q*4 + r;
            cf[r] = coefG[(btbase + t)*64 + e];
            ns[r] = nscG[btbase + t];
        }
        #pragma unroll
        for (int mi = 0; mi < 2; mi++) {
            int nl = 2*wv + mi;
            int ng = n0 + nl;
            float nrv[4], niv[4];
            #pragma unroll
            for (int r = 0; r < 4; r++) {
                int off = (ng*16 + q*4 + r)*64 + e;
                nrv[r] = nzr[off];
                niv[r] = nzi[off];
            }
            float hr = 0.f, hi = 0.f, Apr = 1.f, Api = 0.f;
            float hrs[4], his[4], Aprs[4], Apis[4];
            #pragma unroll
            for (int r = 0; r < 4; r++) {
                float Sr = acc[mi][ni][r] + br;
                float Si = acc[mi][ni+4][r] + bi;
                float ur = Sr*cf[r].z - Si*cf[r].w + ns[r]*nrv[r];
                float ui = Sr*cf[r].w + Si*cf[r].z + ns[r]*niv[r];
                if (r == 0) { hr = ur; hi = ui; Apr = cf[0].x; Api = cf[0].y; }
                else {
                    float tr = cf[r].x*hr - cf[r].y*hi + ur;
                    float ti = cf[r].x*hi + cf[r].y*hr + ui;
                    hr = tr; hi = ti;
                    tr = cf[r].x*Apr - cf[r].y*Api;
                    ti = cf[r].x*Api + cf[r].y*Apr;
                    Apr = tr; Api = ti;
                }
                hrs[r] = hr; his[r] = hi; Aprs[r] = Apr; Apis[r] = Api;
            }
            // quad-prefix over segments (A,H): h_out = H + A*h_in
            float Ar = Apr, Ai = Api, Hr = hr, Hi = hi;
            #pragma unroll
            for (int off = 16; off <= 32; off <<= 1) {
                float pAr = __shfl_up(Ar, off, 64);
                float pAi = __shfl_up(Ai, off, 64);
                float pHr = __shfl_up(Hr, off, 64);
                float pHi = __shfl_up(Hi, off, 64);
                if (l >= off) {
                    Hr = Hr + Ar*pHr - Ai*pHi;
                    Hi = Hi + Ar*pHi + Ai*pHr;
                    float tAr = Ar*pAr - Ai*pAi;
                    float tAi = Ar*pAi + Ai*pAr;
                    Ar = tAr; Ai = tAi;
                }
            }
            float gr = __shfl_up(Hr, 16, 64);
            float gi = __shfl_up(Hi, 16, 64);
            if (q == 0) { gr = 0.f; gi = 0.f; }
            #pragma unroll
            for (int r = 0; r < 4; r++) {
                float fhr = hrs[r] + Aprs[r]*gr - Apis[r]*gi;
                float fhi = his[r] + Aprs[r]*gi + Apis[r]*gr;
                int row = nl*16 + q*4 + r;
                _Float16 hrh = (_Float16)fhr;
                _Float16 hih = (_Float16)fhi;
                *(_Float16*)&At[row*TP + e]        = hrh;
                *(_Float16*)&At[row*TP + 64 + e]   = hih;
                *(_Float16*)&At[row*TP + 128 + e]  = (_Float16)(fhr - (float)hrh);
                *(_Float16*)&At[row*TP + 192 + e]  = (_Float16)(fhi - (float)hih);
            }
        }
    }

    // GEMM2: drift = (h_hi + h_lo) @ BdecX  (K=256, duplicated weights)
    f32x4 acc2[2][4];
    #pragma unroll
    for (int mi = 0; mi < 2; mi++)
        #pragma unroll
        for (int ni = 0; ni < 4; ni++)
            acc2[mi][ni] = (f32x4){0.f,0.f,0.f,0.f};
    #pragma unroll
    for (int ks = 0; ks < 8; ks++) {
        int ko = ks*32 + q*8;
        f16x8 a0 = *(const f16x8*)&At[((2*wv+0)*16 + lm)*TP + ko];
        f16x8 a1 = *(const f16x8*)&At[((2*wv+1)*16 + lm)*TP + ko];
        #pragma unroll
        for (int ni = 0; ni < 4; ni++) {
            f16x8 bb = *(const f16x8*)(BdecX + (ni*16 + lm)*256 + ko);
            acc2[0][ni] = MFMA_F16(a0, bb, acc2[0][ni]);
            acc2[1][ni] = MFMA_F16(a1, bb, acc2[1][ni]);
        }
    }

    // epilogue: xio.re += drift (in place, re-half only)
    #pragma unroll
    for (int mi = 0; mi < 2; mi++) {
        int nl = 2*wv + mi;
        #pragma unroll
        for (int ni = 0; ni < 4; ni++) {
            int d = ni*16 + lm;
            #pragma unroll
            for (int r = 0; r < 4; r++) {
                int t = q*4 + r;
                size_t idx = ((size_t)((b*16 + t)*HW) + hw0 + nl)*128 + d;
                xio[idx] = xio[idx] + acc2[mi][ni][r];
            }
        }
    }
}

// ---------------- Stage 3: MoE FFN via MFMA; 32-token blocks / 2 waves for occupancy ----------
// Round-1 column-split structure (wave owns a 64-col weight strip -> cheap B loads), shrunk to
// 128 threads / 32 tokens / ~18 KB LDS -> 8 blocks/CU. Barriers sync only 2 waves and 7 other
// blocks cover the stall. 2 barriers per expert (GEMM1->GELU barrier is redundant: hidA's last
// reader was fenced by the previous loop-end barrier).
__global__ __launch_bounds__(128, 4) void k_moe_mfma(
    const float* __restrict__ xio,
    float* __restrict__ outp,
    const __hip_bfloat16* __restrict__ rwB, const float* __restrict__ rb,
    const __hip_bfloat16* __restrict__ w1b, const float* __restrict__ b1,
    const __hip_bfloat16* __restrict__ w2b, const float* __restrict__ b2)
{
    __shared__ __align__(16) short smem[2*32*136];   // tokA | hidA; reused as fp32 tile 32x129
    __shared__ float gates[128];
    short* tokA = smem;
    short* hidA = smem + 32*136;
    float* tile = (float*)smem;
    int tok0 = blockIdx.x * 32;
    int tid = threadIdx.x;
    for (int lsd = tid; lsd < 1024; lsd += 128) {
        int t = lsd >> 5, j = lsd & 31;
        float4 v = *(const float4*)&xio[(size_t)(tok0 + t)*128 + j*4];
        union { __hip_bfloat16 h[4]; float2 f; } u;
        u.h[0] = __float2bfloat16(v.x);
        u.h[1] = __float2bfloat16(v.y);
        u.h[2] = __float2bfloat16(v.z);
        u.h[3] = __float2bfloat16(v.w);
        *(float2*)&tokA[t*136 + j*4] = u.f;
    }
    __syncthreads();

    int wv = tid >> 6, l = tid & 63, lm = l & 15, q = l >> 4;
    int n0 = wv * 64;        // this wave's 64-col output strip (4 ni tiles)
    int r0 = wv * 16;        // this wave's router row block

    // Router via MFMA for rows [r0, r0+16); published by the barrier after GELU(e=0).
    {
        f32x4 racc = (f32x4){0.f,0.f,0.f,0.f};
        #pragma unroll
        for (int ks = 0; ks < 4; ks++) {
            int ko = ks*32 + q*8;
            bf16x8 bb = *(const bf16x8*)(rwB + lm*128 + ko);
            bf16x8 a  = *(const bf16x8*)&tokA[(r0 + lm)*136 + ko];
            racc = MFMA_BF16(a, bb, racc);
        }
        float rb_l = rb[lm & 3];
        #pragma unroll
        for (int r = 0; r < 4; r++) {
            float g = racc[r] + rb_l;
            // softmax over experts: lanes lm=0..3 within aligned 4-lane groups
            float mx = fmaxf(g, __shfl_xor(g, 1, 64));
            mx = fmaxf(mx, __shfl_xor(mx, 2, 64));
            float ev = __expf(g - mx);
            float sv = ev + __shfl_xor(ev, 1, 64);
            sv += __shfl_xor(sv, 2, 64);
            if (lm < 4)
                gates[(r0 + q*4 + r)*4 + lm] = ev * __builtin_amdgcn_rcpf(sv);
        }
    }

    f32x4 outa[2][4];
    #pragma unroll
    for (int mi = 0; mi < 2; mi++)
        #pragma unroll
        for (int ni = 0; ni < 4; ni++)
            outa[mi][ni] = (f32x4){0.f,0.f,0.f,0.f};

    #pragma unroll
    for (int e = 0; e < 4; e++) {
        // GEMM1: hid[all 32 rows][n0..n0+64) = tok @ w1[e] strip
        f32x4 acc1[2][4];
        #pragma unroll
        for (int mi = 0; mi < 2; mi++)
            #pragma unroll
            for (int ni = 0; ni < 4; ni++)
                acc1[mi][ni] = (f32x4){0.f,0.f,0.f,0.f};
        const __hip_bfloat16* wp1 = w1b + e*16384;
        #pragma unroll
        for (int ks = 0; ks < 4; ks++) {
            int ko = ks*32 + q*8;
            bf16x8 a0 = *(const bf16x8*)&tokA[(lm)*136 + ko];
            bf16x8 a1 = *(const bf16x8*)&tokA[(16 + lm)*136 + ko];
            #pragma unroll
            for (int ni = 0; ni < 4; ni++) {
                bf16x8 bb = *(const bf16x8*)(wp1 + (n0 + ni*16 + lm)*128 + ko);
                acc1[0][ni] = MFMA_BF16(a0, bb, acc1[0][ni]);
                acc1[1][ni] = MFMA_BF16(a1, bb, acc1[1][ni]);
            }
        }
        // GELU -> hidA own cols, all rows
        #pragma unroll
        for (int ni = 0; ni < 4; ni++) {
            int hcol = n0 + ni*16 + lm;
            float bb = b1[e*128 + hcol];
            #pragma unroll
            for (int mi = 0; mi < 2; mi++) {
                #pragma unroll
                for (int r = 0; r < 4; r++) {
                    float hv = gelu_f(acc1[mi][ni][r] + bb);
                    int m = mi*16 + q*4 + r;
                    *(__hip_bfloat16*)&hidA[m*136 + hcol] = __float2bfloat16(hv);
                }
            }
        }
        __syncthreads();   // publish hidA (and gates on e=0)
        // GEMM2: delta[all rows][n0..n0+64) = hid @ w2[e] strip (contracts all 128 h-cols)
        f32x4 acc2[2][4];
        #pragma unroll
        for (int mi = 0; mi < 2; mi++)
            #pragma unroll
            for (int ni = 0; ni < 4; ni++)
                acc2[mi][ni] = (f32x4){0.f,0.f,0.f,0.f};
        const __hip_bfloat16* wp2 = w2b + e*16384;
        #pragma unroll
        for (int ks = 0; ks < 4; ks++) {
            int ko = ks*32 + q*8;
            bf16x8 a0 = *(const bf16x8*)&hidA[(lm)*136 + ko];
            bf16x8 a1 = *(const bf16x8*)&hidA[(16 + lm)*136 + ko];
            #pragma unroll
            for (int ni = 0; ni < 4; ni++) {
                bf16x8 bb = *(const bf16x8*)(wp2 + (n0 + ni*16 + lm)*128 + ko);
                acc2[0][ni] = MFMA_BF16(a0, bb, acc2[0][ni]);
                acc2[1][ni] = MFMA_BF16(a1, bb, acc2[1][ni]);
            }
        }
        // gate/bias fold
        #pragma unroll
        for (int mi = 0; mi < 2; mi++) {
            float g4[4];
            #pragma unroll
            for (int r = 0; r < 4; r++)
                g4[r] = gates[(mi*16 + q*4 + r)*4 + e];
            #pragma unroll
            for (int ni = 0; ni < 4; ni++) {
                float bb = b2[e*128 + n0 + ni*16 + lm];
                #pragma unroll
                for (int r = 0; r < 4; r++)
                    outa[mi][ni][r] += g4[r] * (acc2[mi][ni][r] + bb);
            }
        }
        __syncthreads();   // hidA readers done before next expert's GELU overwrites
    }

    // final = residual + delta -> LDS tile (pitch 129) -> native-layout store
    #pragma unroll
    for (int ni = 0; ni < 4; ni++) {
        int col = n0 + ni*16 + lm;
        #pragma unroll
        for (int mi = 0; mi < 2; mi++) {
            #pragma unroll
            for (int r = 0; r < 4; r++) {
                int m = mi*16 + q*4 + r;
                tile[m*129 + col] = xio[(size_t)(tok0 + m)*128 + col] + outa[mi][ni][r];
            }
        }
    }
    __syncthreads();
    int bt = tok0 >> 12;
    int hw0 = tok0 & 4095;
    for (int lid = tid; lid < 4096; lid += 128) {
        int c = lid >> 5, m = lid & 31;
        int p = c >> 6, d = c & 63;
        outp[((size_t)((p*32 + bt)*64 + d))*HW + hw0 + m] = tile[m*129 + c];
    }
}

extern "C" void kernel_launch(void* const* d_in, const int* in_sizes, int n_in,
                              void* d_out, int out_size, void* d_ws, size_t ws_size,
                              hipStream_t stream)
{
    const float* x_real = (const float*)d_in[0];
    const float* x_imag = (const float*)d_in[1];
    const float* dt     = (const float*)d_in[2];
    const float* nzr    = (const float*)d_in[3];
    const float* nzi    = (const float*)d_in[4];
    const float* ln_s_w = (const float*)d_in[5];
    const float* ln_s_b = (const float*)d_in[6];
    const float* conv_w = (const float*)d_in[7];
    const float* conv_b = (const float*)d_in[8];
    const float* ln_t_w = (const float*)d_in[9];
    const float* ln_t_b = (const float*)d_in[10];
    const float* lam_re = (const float*)d_in[11];
    const float* lam_im = (const float*)d_in[12];
    const float* sbr    = (const float*)d_in[13];
    const float* sbi    = (const float*)d_in[14];
    const float* enc_re = (const float*)d_in[15];
    const float* enc_im = (const float*)d_in[16];
    const float* dec_re = (const float*)d_in[17];
    const float* dec_im = (const float*)d_in[18];
    const float* rw     = (const float*)d_in[19];
    const float* rb     = (const float*)d_in[20];
    const float* w1     = (const float*)d_in[21];
    const float* b1     = (const float*)d_in[22];
    const float* w2     = (const float*)d_in[23];
    const float* b2     = (const float*)d_in[24];

    char* ws = (char*)d_ws;
    float* bufA = (float*)ws;                                              // 64 MiB fp32 layout-A
    __hip_bfloat16* bufB = (__hip_bfloat16*)(ws + (size_t)64*1024*1024);   // 32 MiB bf16 (ln_s -> conv)
    __hip_bfloat16* wBc  = (__hip_bfloat16*)(ws + (size_t)96*1024*1024);   // conv weights [9][oc][ic]
    __hip_bfloat16* w1b  = wBc + 9*16384;
    __hip_bfloat16* w2b  = w1b + 4*16384;
    _Float16* Benc  = (_Float16*)(w2b + 4*16384);                          // [128][128] f16
    _Float16* BdecX = Benc + 16384;                                        // [64][256] f16
    float4* coefG = (float4*)(BdecX + 16384);                              // [2048]
    float* nscG   = (float*)(coefG + 2048);                                // [32]
    __hip_bfloat16* rwB = (__hip_bfloat16*)(nscG + 32);                    // [16][128] bf16 router
    float* outp = (float*)d_out;

    k_prep_t  <<<dim3(9,16), 256, 0, stream>>>(conv_w, wBc);
    k_prep_t  <<<dim3(4,16), 256, 0, stream>>>(w1, w1b);
    k_prep_t  <<<dim3(4,16), 256, 0, stream>>>(w2, w2b);
    k_prep_enc<<<64,         256, 0, stream>>>(enc_re, enc_im, dec_re, dec_im,
                                               dt, lam_re, lam_im, rw,
                                               Benc, BdecX, coefG, nscG, rwB);

    k_ln_s         <<<dim3(32,64), 256, 0, stream>>>(x_real, x_imag, ln_s_w, ln_s_b, bufB);
    k_conv_mfma    <<<dim3(32,64), 256, 0, stream>>>(bufB, wBc, conv_b, x_real, x_imag, bufA);
    k_temporal_mfma<<<2048,        128, 0, stream>>>(bufA, ln_t_w, ln_t_b, sbr, sbi,
                                                     Benc, BdecX, coefG, nscG, nzr, nzi);
    k_moe_mfma     <<<4096,        128, 0, stream>>>(bufA, outp, rwB, rb, w1b, b1, w2b, b2);
}

// Round 10
// 504.566 us; speedup vs baseline: 1.4071x; 1.2118x over previous
//
#include <hip/hip_runtime.h>
#include <hip/hip_bf16.h>
#include <math.h>

#define HW 4096
#define TP 264   // temporal A-tile pitch in halves: 528 B row stride == 4 mod 32 banks (2-way, free)

typedef __attribute__((ext_vector_type(8))) short bf16x8;
typedef _Float16 f16x8 __attribute__((ext_vector_type(8)));
typedef __attribute__((ext_vector_type(4))) float f32x4;

#define MFMA_BF16(a, b, c) __builtin_amdgcn_mfma_f32_16x16x32_bf16((a), (b), (c), 0, 0, 0)
#define MFMA_F16(a, b, c)  __builtin_amdgcn_mfma_f32_16x16x32_f16((a), (b), (c), 0, 0, 0)

static __device__ __forceinline__ float gelu_f(float xv) {
    // tanh-gelu via sigmoid identity: 0.5x(1+tanh(t)) = x*e/(e+1), e=exp(2t)
    float x2 = xv*xv;
    float t2 = xv*(1.5957691216057308f + 0.07135481627260025f*x2);
    float ee = __expf(t2);
    return xv*(1.f - __builtin_amdgcn_rcpf(ee + 1.f));
}

// ---------------- Prep: fp32 [nmat][128][128] -> bf16 [nmat][128][128] transposed ----------------
__global__ __launch_bounds__(256) void k_prep_t(
    const float* __restrict__ src, __hip_bfloat16* __restrict__ dst)
{
    __shared__ float t[32*33];
    int m  = blockIdx.x;
    int tr = blockIdx.y >> 2, tc = blockIdx.y & 3;
    int tid = threadIdx.x;
    for (int l = tid; l < 1024; l += 256) {
        int r = l >> 5, c = l & 31;
        t[r*33 + c] = src[m*16384 + (tr*32 + r)*128 + (tc*32 + c)];
    }
    __syncthreads();
    for (int l = tid; l < 1024; l += 256) {
        int c = l >> 5, r = l & 31;
        dst[m*16384 + (tc*32 + c)*128 + (tr*32 + r)] = __float2bfloat16(t[r*33 + c]);
    }
}

// ---------------- Prep: temporal tables + router weight tile ----------------
// Benc  f16 [128n][128k]: n<64 -> u_re col e: [Er[k][e] | -Ei[k-64][e]]
//                         n>=64 -> u_im col e: [Ei[k][e] |  Er[k-64][e]]
// BdecX f16 [64n][256k] : k and k+128 hold the SAME value (hi/lo split accumulation)
//                         base (k<128): [Dr[k][d] | -Di[k-64][d]]
// coefG float4[(b*16+t)*64+e] = (a_re, a_im, f_re, f_im);  nscG[b*16+t] = 0.01*sqrt(dt)
// rwB   bf16 [16n][128k]: n<4 -> router_w[k][n], rest zero (router as MFMA B-operand)
__global__ __launch_bounds__(256) void k_prep_enc(
    const float* __restrict__ encr, const float* __restrict__ enci,
    const float* __restrict__ decr, const float* __restrict__ deci,
    const float* __restrict__ dt,
    const float* __restrict__ lamr, const float* __restrict__ lami,
    const float* __restrict__ rw,
    _Float16* __restrict__ Benc, _Float16* __restrict__ BdecX,
    float4* __restrict__ coefG, float* __restrict__ nscG,
    __hip_bfloat16* __restrict__ rwB)
{
    int idx = blockIdx.x*256 + threadIdx.x;
    if (idx < 16384) {
        int n = idx >> 7, k = idx & 127;
        int e = n & 63, d = k & 63;
        float v;
        if (n < 64) v = (k < 64) ? encr[d*64 + e] : -enci[d*64 + e];
        else        v = (k < 64) ? enci[d*64 + e] :  encr[d*64 + e];
        Benc[idx] = (_Float16)v;
    }
    if (idx < 16384) {
        int n = idx >> 8, k = idx & 255;
        int kk = k & 127;
        int e = kk & 63;
        float v = (kk < 64) ? decr[e*64 + n] : -deci[e*64 + n];
        BdecX[idx] = (_Float16)v;
    }
    if (idx < 2048) {
        int bt = idx >> 6, e = idx & 63;
        float dtv = dt[bt];
        float lr = lamr[e];
        float sp = (lr > 20.f) ? lr : log1pf(expf(lr));
        float lre = -sp, lim = lami[e];
        float inv = 1.f / (lre*lre + lim*lim);
        float ex = expf(lre*dtv);
        float sn, cs; sincosf(lim*dtv, &sn, &cs);
        float ar = ex*cs, ai = ex*sn;
        float fr = ((ar - 1.f)*lre + ai*lim)*inv;
        float fi = (ai*lre - (ar - 1.f)*lim)*inv;
        coefG[idx] = make_float4(ar, ai, fr, fi);
    }
    if (idx < 2048) {
        int n = idx >> 7, k = idx & 127;
        float v = (n < 4) ? rw[k*4 + n] : 0.f;
        rwB[idx] = __float2bfloat16(v);
    }
    if (idx < 32) nscG[idx] = 0.01f * sqrtf(dt[idx]);
}

// ---------------- Stage 1a: spatial complex LayerNorm -> bf16 layout-A ----------------
__global__ __launch_bounds__(256) void k_ln_s(
    const float* __restrict__ xr, const float* __restrict__ xi,
    const float* __restrict__ lw, const float* __restrict__ lb,
    __hip_bfloat16* __restrict__ out)
{
    __shared__ float tile[64*129];
    __shared__ float ps[64*4];
    __shared__ float ps2[64*4];
    __shared__ float mu_s[64];
    __shared__ float rs_s[64];
    int bt  = blockIdx.x;
    int hw0 = blockIdx.y * 64;
    int tid = threadIdx.x;
    int wl = tid & 63;
    int q  = tid >> 6;
    float s = 0.f, s2 = 0.f;
    for (int c = q; c < 128; c += 4) {
        const float* src = (c < 64) ? xr : xi;
        int d = c & 63;
        float v = src[(bt*64 + d)*HW + hw0 + wl];
        tile[wl*129 + c] = v;
        s += v; s2 += v*v;
    }
    ps[wl*4 + q] = s;
    ps2[wl*4 + q] = s2;
    __syncthreads();
    if (tid < 64) {
        float ss = ps[tid*4+0]+ps[tid*4+1]+ps[tid*4+2]+ps[tid*4+3];
        float qq = ps2[tid*4+0]+ps2[tid*4+1]+ps2[tid*4+2]+ps2[tid*4+3];
        float mu = ss * 0.0078125f;
        float var = qq * 0.0078125f - mu*mu;
        mu_s[tid] = mu;
        rs_s[tid] = rsqrtf(var + 1e-5f);
    }
    __syncthreads();
    int c = tid & 127;
    int r = tid >> 7;
    float wc = lw[c], bc = lb[c];
    for (int wi = r; wi < 64; wi += 2) {
        float v = tile[wi*129 + c];
        out[(size_t)(bt*HW + hw0 + wi)*128 + c] =
            __float2bfloat16((v - mu_s[wi]) * rs_s[wi] * wc + bc);
    }
}

// ---------------- Stage 1b: 3x3 conv via MFMA implicit GEMM + bias + residual ----------------
__global__ __launch_bounds__(256) void k_conv_mfma(
    const __hip_bfloat16* __restrict__ xc,
    const __hip_bfloat16* __restrict__ wB,
    const float* __restrict__ cb,
    const float* __restrict__ xr, const float* __restrict__ xi,
    float* __restrict__ x1)
{
    __shared__ __align__(16) short inrow[3*66*136];
    int bt = blockIdx.x, h = blockIdx.y;
    int tid = threadIdx.x;
    if (tid < 96) {
        int r = tid / 32, t2 = tid & 31;
        int px = (t2 & 1) ? 65 : 0;
        int j = t2 >> 1;
        *(float4*)&inrow[(r*66 + px)*136 + j*8] = make_float4(0.f,0.f,0.f,0.f);
    }
    for (int c = tid; c < 3072; c += 256) {
        int r   = c >> 10;
        int rem = c & 1023;
        int px  = rem >> 4;
        int j   = rem & 15;
        int gh  = h + r - 1;
        float4 v = make_float4(0.f,0.f,0.f,0.f);
        if ((unsigned)gh < 64u)
            v = *(const float4*)&xc[(size_t)((bt*HW + gh*64 + px)*128) + j*8];
        *(float4*)&inrow[(r*66 + px + 1)*136 + j*8] = v;
    }
    __syncthreads();

    int wv = tid >> 6, l = tid & 63, lm = l & 15, q = l >> 4;
    int n0 = wv * 32;
    f32x4 acc[4][2];
    #pragma unroll
    for (int mi = 0; mi < 4; mi++)
        #pragma unroll
        for (int ni = 0; ni < 2; ni++)
            acc[mi][ni] = (f32x4){0.f,0.f,0.f,0.f};

    for (int p = 0; p < 9; p++) {
        int kh = p / 3, kw = p - kh*3;
        const __hip_bfloat16* wp = wB + p*16384;
        int abase = (kh*66 + kw)*136;
        #pragma unroll
        for (int ks = 0; ks < 4; ks++) {
            int ko = ks*32 + q*8;
            bf16x8 b0 = *(const bf16x8*)(wp + (n0 + lm)*128 + ko);
            bf16x8 b1 = *(const bf16x8*)(wp + (n0 + 16 + lm)*128 + ko);
            #pragma unroll
            for (int mi = 0; mi < 4; mi++) {
                bf16x8 a = *(const bf16x8*)&inrow[abase + (mi*16 + lm)*136 + ko];
                acc[mi][0] = MFMA_BF16(a, b0, acc[mi][0]);
                acc[mi][1] = MFMA_BF16(a, b1, acc[mi][1]);
            }
        }
    }
    #pragma unroll
    for (int ni = 0; ni < 2; ni++) {
        int oc = n0 + ni*16 + lm;
        float bias = cb[oc];
        const float* rsp = (oc < 64) ? xr : xi;
        const float* rbase = &rsp[(bt*64 + (oc & 63))*HW + h*64];
        #pragma unroll
        for (int mi = 0; mi < 4; mi++) {
            #pragma unroll
            for (int r = 0; r < 4; r++) {
                int w = mi*16 + q*4 + r;
                x1[(size_t)(bt*HW + h*64 + w)*128 + oc] = acc[mi][ni][r] + bias + rbase[w];
            }
        }
    }
}

// ---------------- Stage 2: temporal via MFMA, f16 + hi/lo-split decode ----------------
// block = 128 thr / 2 waves, 4 pixels. A-tile 64 rows = (n_local,t), pitch 264:
// cols 0..127 = z then h_hi [re|im]; cols 128..255 = h_lo [re|im].
// GEMM1 (encode, K=128) -> in-fragment complex scan -> h hi/lo to tile -> GEMM2 (decode, K=256).
__global__ __launch_bounds__(128) void k_temporal_mfma(
    float* xio,
    const float* __restrict__ lw, const float* __restrict__ lb,
    const float* __restrict__ sbr, const float* __restrict__ sbi,
    const _Float16* __restrict__ Benc, const _Float16* __restrict__ BdecX,
    const float4* __restrict__ coefG, const float* __restrict__ nscG,
    const float* __restrict__ nzr, const float* __restrict__ nzi)
{
    __shared__ __align__(16) short At[64*TP];   // 33792 B
    int n0  = blockIdx.x * 4;
    int b   = n0 >> 12;
    int hw0 = n0 & 4095;
    int tid = threadIdx.x;

    // LN: 2 threads per row (row = n_local*16 + t), f16 into A-tile cols 0..127
    {
        int row = tid >> 1, half = tid & 1;
        int nl = row >> 4, t = row & 15;
        const float4* src = (const float4*)&xio[((size_t)((b*16 + t)*HW) + hw0 + nl)*128 + half*64];
        float4 v[16];
        float s = 0.f, s2 = 0.f;
        #pragma unroll
        for (int j = 0; j < 16; j++) {
            v[j] = src[j];
            s  += v[j].x + v[j].y + v[j].z + v[j].w;
            s2 += v[j].x*v[j].x + v[j].y*v[j].y + v[j].z*v[j].z + v[j].w*v[j].w;
        }
        s  += __shfl_xor(s, 1, 64);
        s2 += __shfl_xor(s2, 1, 64);
        float mu  = s * 0.0078125f;
        float var = s2 * 0.0078125f - mu*mu;
        float rsq = rsqrtf(var + 1e-5f);
        const float4* lw4 = (const float4*)(lw + half*64);
        const float4* lb4 = (const float4*)(lb + half*64);
        short* dstrow = &At[row*TP + half*64];
        #pragma unroll
        for (int j = 0; j < 16; j++) {
            float4 wv4 = lw4[j], bv = lb4[j];
            union { _Float16 h[4]; float2 f; } u;
            u.h[0] = (_Float16)((v[j].x - mu)*rsq*wv4.x + bv.x);
            u.h[1] = (_Float16)((v[j].y - mu)*rsq*wv4.y + bv.y);
            u.h[2] = (_Float16)((v[j].z - mu)*rsq*wv4.z + bv.z);
            u.h[3] = (_Float16)((v[j].w - mu)*rsq*wv4.w + bv.w);
            *(float2*)(dstrow + j*4) = u.f;
        }
    }
    __syncthreads();   // coef/LN cross-wave publish; tile rows are wave-private below

    int wv = tid >> 6, l = tid & 63, lm = l & 15, q = l >> 4;

    // GEMM1: u_pre = z @ Benc  (ni<4 = re cols, ni+4 = im cols)
    f32x4 acc[2][8];
    #pragma unroll
    for (int mi = 0; mi < 2; mi++)
        #pragma unroll
        for (int ni = 0; ni < 8; ni++)
            acc[mi][ni] = (f32x4){0.f,0.f,0.f,0.f};
    #pragma unroll
    for (int ks = 0; ks < 4; ks++) {
        int ko = ks*32 + q*8;
        f16x8 a0 = *(const f16x8*)&At[((2*wv+0)*16 + lm)*TP + ko];
        f16x8 a1 = *(const f16x8*)&At[((2*wv+1)*16 + lm)*TP + ko];
        #pragma unroll
        for (int ni = 0; ni < 8; ni++) {
            f16x8 bb = *(const f16x8*)(Benc + (ni*16 + lm)*128 + ko);
            acc[0][ni] = MFMA_F16(a0, bb, acc[0][ni]);
            acc[1][ni] = MFMA_F16(a1, bb, acc[1][ni]);
        }
    }

    // in-fragment complex scan (coef from global table); write h hi/lo into wave rows
    int btbase = b*16;
    #pragma unroll
    for (int ni = 0; ni < 4; ni++) {
        int e = ni*16 + lm;
        float br = sbr[e], bi = sbi[e];
        float4 cf[4]; float ns[4];
        #pragma unroll
        for (int r = 0; r < 4; r++) {
            int t = q*4 + r;
            cf[r] = coefG[(btbase + t)*64 + e];
            ns[r] = nscG[btbase + t];
        }
        #pragma unroll
        for (int mi = 0; mi < 2; mi++) {
            int nl = 2*wv + mi;
            int ng = n0 + nl;
            float nrv[4], niv[4];
            #pragma unroll
            for (int r = 0; r < 4; r++) {
                int off = (ng*16 + q*4 + r)*64 + e;
                nrv[r] = nzr[off];
                niv[r] = nzi[off];
            }
            float hr = 0.f, hi = 0.f, Apr = 1.f, Api = 0.f;
            float hrs[4], his[4], Aprs[4], Apis[4];
            #pragma unroll
            for (int r = 0; r < 4; r++) {
                float Sr = acc[mi][ni][r] + br;
                float Si = acc[mi][ni+4][r] + bi;
                float ur = Sr*cf[r].z - Si*cf[r].w + ns[r]*nrv[r];
                float ui = Sr*cf[r].w + Si*cf[r].z + ns[r]*niv[r];
                if (r == 0) { hr = ur; hi = ui; Apr = cf[0].x; Api = cf[0].y; }
                else {
                    float tr = cf[r].x*hr - cf[r].y*hi + ur;
                    float ti = cf[r].x*hi + cf[r].y*hr + ui;
                    hr = tr; hi = ti;
                    tr = cf[r].x*Apr - cf[r].y*Api;
                    ti = cf[r].x*Api + cf[r].y*Apr;
                    Apr = tr; Api = ti;
                }
                hrs[r] = hr; his[r] = hi; Aprs[r] = Apr; Apis[r] = Api;
            }
            // quad-prefix over segments (A,H): h_out = H + A*h_in
            float Ar = Apr, Ai = Api, Hr = hr, Hi = hi;
            #pragma unroll
            for (int off = 16; off <= 32; off <<= 1) {
                float pAr = __shfl_up(Ar, off, 64);
                float pAi = __shfl_up(Ai, off, 64);
                float pHr = __shfl_up(Hr, off, 64);
                float pHi = __shfl_up(Hi, off, 64);
                if (l >= off) {
                    Hr = Hr + Ar*pHr - Ai*pHi;
                    Hi = Hi + Ar*pHi + Ai*pHr;
                    float tAr = Ar*pAr - Ai*pAi;
                    float tAi = Ar*pAi + Ai*pAr;
                    Ar = tAr; Ai = tAi;
                }
            }
            float gr = __shfl_up(Hr, 16, 64);
            float gi = __shfl_up(Hi, 16, 64);
            if (q == 0) { gr = 0.f; gi = 0.f; }
            #pragma unroll
            for (int r = 0; r < 4; r++) {
                float fhr = hrs[r] + Aprs[r]*gr - Apis[r]*gi;
                float fhi = his[r] + Aprs[r]*gi + Apis[r]*gr;
                int row = nl*16 + q*4 + r;
                _Float16 hrh = (_Float16)fhr;
                _Float16 hih = (_Float16)fhi;
                *(_Float16*)&At[row*TP + e]        = hrh;
                *(_Float16*)&At[row*TP + 64 + e]   = hih;
                *(_Float16*)&At[row*TP + 128 + e]  = (_Float16)(fhr - (float)hrh);
                *(_Float16*)&At[row*TP + 192 + e]  = (_Float16)(fhi - (float)hih);
            }
        }
    }

    // GEMM2: drift = (h_hi + h_lo) @ BdecX  (K=256, duplicated weights)
    f32x4 acc2[2][4];
    #pragma unroll
    for (int mi = 0; mi < 2; mi++)
        #pragma unroll
        for (int ni = 0; ni < 4; ni++)
            acc2[mi][ni] = (f32x4){0.f,0.f,0.f,0.f};
    #pragma unroll
    for (int ks = 0; ks < 8; ks++) {
        int ko = ks*32 + q*8;
        f16x8 a0 = *(const f16x8*)&At[((2*wv+0)*16 + lm)*TP + ko];
        f16x8 a1 = *(const f16x8*)&At[((2*wv+1)*16 + lm)*TP + ko];
        #pragma unroll
        for (int ni = 0; ni < 4; ni++) {
            f16x8 bb = *(const f16x8*)(BdecX + (ni*16 + lm)*256 + ko);
            acc2[0][ni] = MFMA_F16(a0, bb, acc2[0][ni]);
            acc2[1][ni] = MFMA_F16(a1, bb, acc2[1][ni]);
        }
    }

    // epilogue: xio.re += drift (in place, re-half only)
    #pragma unroll
    for (int mi = 0; mi < 2; mi++) {
        int nl = 2*wv + mi;
        #pragma unroll
        for (int ni = 0; ni < 4; ni++) {
            int d = ni*16 + lm;
            #pragma unroll
            for (int r = 0; r < 4; r++) {
                int t = q*4 + r;
                size_t idx = ((size_t)((b*16 + t)*HW) + hw0 + nl)*128 + d;
                xio[idx] = xio[idx] + acc2[mi][ni][r];
            }
        }
    }
}

// ---------------- Stage 3: MoE FFN via MFMA (round-1 structure, redundant barrier removed) ----
// 256 thr / 64 tokens / 35.8 KB LDS — measured-best topology (114 us). Column-split: wave owns
// a 32-col weight strip (2 B-fragments per k-step). Barriers: stage(1) + 2/expert (post-GELU,
// loop-end) + tail(2) = 11. The old GEMM1->GELU barrier was redundant: GELU(e)'s hidA writes
// are fenced against GEMM2(e-1)'s reads by the loop-end barrier of iteration e-1.
__global__ __launch_bounds__(256) void k_moe_mfma(
    const float* __restrict__ xio,
    float* __restrict__ outp,
    const __hip_bfloat16* __restrict__ rwB, const float* __restrict__ rb,
    const __hip_bfloat16* __restrict__ w1b, const float* __restrict__ b1,
    const __hip_bfloat16* __restrict__ w2b, const float* __restrict__ b2)
{
    __shared__ __align__(16) short smem[2*64*136];   // tokA | hidA; reused as fp32 tile 64x129
    __shared__ float gates[256];
    short* tokA = smem;
    short* hidA = smem + 64*136;
    float* tile = (float*)smem;
    int tok0 = blockIdx.x * 64;
    int tid = threadIdx.x;
    for (int lsd = tid; lsd < 2048; lsd += 256) {
        int t = lsd >> 5, j = lsd & 31;
        float4 v = *(const float4*)&xio[(size_t)(tok0 + t)*128 + j*4];
        union { __hip_bfloat16 h[4]; float2 f; } u;
        u.h[0] = __float2bfloat16(v.x);
        u.h[1] = __float2bfloat16(v.y);
        u.h[2] = __float2bfloat16(v.z);
        u.h[3] = __float2bfloat16(v.w);
        *(float2*)&tokA[t*136 + j*4] = u.f;
    }
    __syncthreads();

    int wv = tid >> 6, l = tid & 63, lm = l & 15, q = l >> 4;
    int n0 = wv * 32;

    // Router via MFMA: wave wv computes logits for token rows [n0, n0+32).
    // gates published to other waves by the post-GELU barrier of expert 0.
    {
        f32x4 racc[2];
        racc[0] = (f32x4){0.f,0.f,0.f,0.f};
        racc[1] = (f32x4){0.f,0.f,0.f,0.f};
        #pragma unroll
        for (int ks = 0; ks < 4; ks++) {
            int ko = ks*32 + q*8;
            bf16x8 bb = *(const bf16x8*)(rwB + lm*128 + ko);
            bf16x8 a0 = *(const bf16x8*)&tokA[(n0 + lm)*136 + ko];
            bf16x8 a1 = *(const bf16x8*)&tokA[(n0 + 16 + lm)*136 + ko];
            racc[0] = MFMA_BF16(a0, bb, racc[0]);
            racc[1] = MFMA_BF16(a1, bb, racc[1]);
        }
        float rb_l = rb[lm & 3];
        #pragma unroll
        for (int mi = 0; mi < 2; mi++) {
            #pragma unroll
            for (int r = 0; r < 4; r++) {
                float g = racc[mi][r] + rb_l;
                float mx = fmaxf(g, __shfl_xor(g, 1, 64));
                mx = fmaxf(mx, __shfl_xor(mx, 2, 64));
                float ev = __expf(g - mx);
                float sv = ev + __shfl_xor(ev, 1, 64);
                sv += __shfl_xor(sv, 2, 64);
                if (lm < 4)
                    gates[(n0 + mi*16 + q*4 + r)*4 + lm] = ev * __builtin_amdgcn_rcpf(sv);
            }
        }
    }

    f32x4 outa[4][2];
    #pragma unroll
    for (int mi = 0; mi < 4; mi++)
        #pragma unroll
        for (int ni = 0; ni < 2; ni++)
            outa[mi][ni] = (f32x4){0.f,0.f,0.f,0.f};

    for (int e = 0; e < 4; e++) {
        // GEMM1: hid[all 64 rows][n0..n0+32) = tok @ w1[e] strip  (reads tokA only)
        f32x4 acc1[4][2];
        #pragma unroll
        for (int mi = 0; mi < 4; mi++)
            #pragma unroll
            for (int ni = 0; ni < 2; ni++)
                acc1[mi][ni] = (f32x4){0.f,0.f,0.f,0.f};
        const __hip_bfloat16* wp1 = w1b + e*16384;
        #pragma unroll
        for (int ks = 0; ks < 4; ks++) {
            int ko = ks*32 + q*8;
            bf16x8 b0  = *(const bf16x8*)(wp1 + (n0 + lm)*128 + ko);
            bf16x8 b1v = *(const bf16x8*)(wp1 + (n0 + 16 + lm)*128 + ko);
            #pragma unroll
            for (int mi = 0; mi < 4; mi++) {
                bf16x8 a = *(const bf16x8*)&tokA[(mi*16 + lm)*136 + ko];
                acc1[mi][0] = MFMA_BF16(a, b0,  acc1[mi][0]);
                acc1[mi][1] = MFMA_BF16(a, b1v, acc1[mi][1]);
            }
        }
        // GELU -> hidA own cols (writes fenced vs GEMM2(e-1) by loop-end barrier)
        #pragma unroll
        for (int ni = 0; ni < 2; ni++) {
            int hcol = n0 + ni*16 + lm;
            float bb = b1[e*128 + hcol];
            #pragma unroll
            for (int mi = 0; mi < 4; mi++) {
                #pragma unroll
                for (int r = 0; r < 4; r++) {
                    float hv = gelu_f(acc1[mi][ni][r] + bb);
                    int m = mi*16 + q*4 + r;
                    *(__hip_bfloat16*)&hidA[m*136 + hcol] = __float2bfloat16(hv);
                }
            }
        }
        __syncthreads();   // publish hidA (and gates on e=0)
        // GEMM2: delta[all rows][n0..n0+32) = hid @ w2[e] strip (contracts all 128 h-cols)
        f32x4 acc2[4][2];
        #pragma unroll
        for (int mi = 0; mi < 4; mi++)
            #pragma unroll
            for (int ni = 0; ni < 2; ni++)
                acc2[mi][ni] = (f32x4){0.f,0.f,0.f,0.f};
        const __hip_bfloat16* wp2 = w2b + e*16384;
        #pragma unroll
        for (int ks = 0; ks < 4; ks++) {
            int ko = ks*32 + q*8;
            bf16x8 b0  = *(const bf16x8*)(wp2 + (n0 + lm)*128 + ko);
            bf16x8 b1v = *(const bf16x8*)(wp2 + (n0 + 16 + lm)*128 + ko);
            #pragma unroll
            for (int mi = 0; mi < 4; mi++) {
                bf16x8 a = *(const bf16x8*)&hidA[(mi*16 + lm)*136 + ko];
                acc2[mi][0] = MFMA_BF16(a, b0,  acc2[mi][0]);
                acc2[mi][1] = MFMA_BF16(a, b1v, acc2[mi][1]);
            }
        }
        #pragma unroll
        for (int ni = 0; ni < 2; ni++) {
            int ocol = n0 + ni*16 + lm;
            float bb = b2[e*128 + ocol];
            #pragma unroll
            for (int mi = 0; mi < 4; mi++) {
                #pragma unroll
                for (int r = 0; r < 4; r++) {
                    int m = mi*16 + q*4 + r;
                    float g = gates[m*4 + e];
                    outa[mi][ni][r] += g * (acc2[mi][ni][r] + bb);
                }
            }
        }
        __syncthreads();   // hidA readers done before next expert's GELU overwrites
    }

    // final = residual + delta -> LDS tile (pitch 129) -> native-layout store
    #pragma unroll
    for (int ni = 0; ni < 2; ni++) {
        int col = n0 + ni*16 + lm;
        #pragma unroll
        for (int mi = 0; mi < 4; mi++) {
            #pragma unroll
            for (int r = 0; r < 4; r++) {
                int m = mi*16 + q*4 + r;
                tile[m*129 + col] = xio[(size_t)(tok0 + m)*128 + col] + outa[mi][ni][r];
            }
        }
    }
    __syncthreads();
    int bt = tok0 >> 12;
    int hw0 = tok0 & 4095;
    for (int lid = tid; lid < 8192; lid += 256) {
        int c = lid >> 6, m = lid & 63;
        int p = c >> 6, d = c & 63;
        outp[((size_t)((p*32 + bt)*64 + d))*HW + hw0 + m] = tile[m*129 + c];
    }
}

extern "C" void kernel_launch(void* const* d_in, const int* in_sizes, int n_in,
                              void* d_out, int out_size, void* d_ws, size_t ws_size,
                              hipStream_t stream)
{
    const float* x_real = (const float*)d_in[0];
    const float* x_imag = (const float*)d_in[1];
    const float* dt     = (const float*)d_in[2];
    const float* nzr    = (const float*)d_in[3];
    const float* nzi    = (const float*)d_in[4];
    const float* ln_s_w = (const float*)d_in[5];
    const float* ln_s_b = (const float*)d_in[6];
    const float* conv_w = (const float*)d_in[7];
    const float* conv_b = (const float*)d_in[8];
    const float* ln_t_w = (const float*)d_in[9];
    const float* ln_t_b = (const float*)d_in[10];
    const float* lam_re = (const float*)d_in[11];
    const float* lam_im = (const float*)d_in[12];
    const float* sbr    = (const float*)d_in[13];
    const float* sbi    = (const float*)d_in[14];
    const float* enc_re = (const float*)d_in[15];
    const float* enc_im = (const float*)d_in[16];
    const float* dec_re = (const float*)d_in[17];
    const float* dec_im = (const float*)d_in[18];
    const float* rw     = (const float*)d_in[19];
    const float* rb     = (const float*)d_in[20];
    const float* w1     = (const float*)d_in[21];
    const float* b1     = (const float*)d_in[22];
    const float* w2     = (const float*)d_in[23];
    const float* b2     = (const float*)d_in[24];

    char* ws = (char*)d_ws;
    float* bufA = (float*)ws;                                              // 64 MiB fp32 layout-A
    __hip_bfloat16* bufB = (__hip_bfloat16*)(ws + (size_t)64*1024*1024);   // 32 MiB bf16 (ln_s -> conv)
    __hip_bfloat16* wBc  = (__hip_bfloat16*)(ws + (size_t)96*1024*1024);   // conv weights [9][oc][ic]
    __hip_bfloat16* w1b  = wBc + 9*16384;
    __hip_bfloat16* w2b  = w1b + 4*16384;
    _Float16* Benc  = (_Float16*)(w2b + 4*16384);                          // [128][128] f16
    _Float16* BdecX = Benc + 16384;                                        // [64][256] f16
    float4* coefG = (float4*)(BdecX + 16384);                              // [2048]
    float* nscG   = (float*)(coefG + 2048);                                // [32]
    __hip_bfloat16* rwB = (__hip_bfloat16*)(nscG + 32);                    // [16][128] bf16 router
    float* outp = (float*)d_out;

    k_prep_t  <<<dim3(9,16), 256, 0, stream>>>(conv_w, wBc);
    k_prep_t  <<<dim3(4,16), 256, 0, stream>>>(w1, w1b);
    k_prep_t  <<<dim3(4,16), 256, 0, stream>>>(w2, w2b);
    k_prep_enc<<<64,         256, 0, stream>>>(enc_re, enc_im, dec_re, dec_im,
                                               dt, lam_re, lam_im, rw,
                                               Benc, BdecX, coefG, nscG, rwB);

    k_ln_s         <<<dim3(32,64), 256, 0, stream>>>(x_real, x_imag, ln_s_w, ln_s_b, bufB);
    k_conv_mfma    <<<dim3(32,64), 256, 0, stream>>>(bufB, wBc, conv_b, x_real, x_imag, bufA);
    k_temporal_mfma<<<2048,        128, 0, stream>>>(bufA, ln_t_w, ln_t_b, sbr, sbi,
                                                     Benc, BdecX, coefG, nscG, nzr, nzi);
    k_moe_mfma     <<<2048,        256, 0, stream>>>(bufA, outp, rwB, rb, w1b, b1, w2b, b2);
}

// Round 11
// 471.619 us; speedup vs baseline: 1.5054x; 1.0699x over previous
//
#include <hip/hip_runtime.h>
#include <hip/hip_bf16.h>
#include <math.h>

#define HW 4096
#define TP 264   // temporal A-tile pitch in halves: 528 B row stride == 4 mod 32 banks (2-way, free)

typedef __attribute__((ext_vector_type(8))) short bf16x8;
typedef _Float16 f16x8 __attribute__((ext_vector_type(8)));
typedef __attribute__((ext_vector_type(4))) float f32x4;

#define MFMA_BF16(a, b, c) __builtin_amdgcn_mfma_f32_16x16x32_bf16((a), (b), (c), 0, 0, 0)
#define MFMA_F16(a, b, c)  __builtin_amdgcn_mfma_f32_16x16x32_f16((a), (b), (c), 0, 0, 0)

static __device__ __forceinline__ float gelu_f(float xv) {
    // tanh-gelu via sigmoid identity: 0.5x(1+tanh(t)) = x*e/(e+1), e=exp(2t)
    float x2 = xv*xv;
    float t2 = xv*(1.5957691216057308f + 0.07135481627260025f*x2);
    float ee = __expf(t2);
    return xv*(1.f - __builtin_amdgcn_rcpf(ee + 1.f));
}

// ---------------- Prep: fp32 [nmat][128][128] -> bf16 [nmat][128][128] transposed ----------------
__global__ __launch_bounds__(256) void k_prep_t(
    const float* __restrict__ src, __hip_bfloat16* __restrict__ dst)
{
    __shared__ float t[32*33];
    int m  = blockIdx.x;
    int tr = blockIdx.y >> 2, tc = blockIdx.y & 3;
    int tid = threadIdx.x;
    for (int l = tid; l < 1024; l += 256) {
        int r = l >> 5, c = l & 31;
        t[r*33 + c] = src[m*16384 + (tr*32 + r)*128 + (tc*32 + c)];
    }
    __syncthreads();
    for (int l = tid; l < 1024; l += 256) {
        int c = l >> 5, r = l & 31;
        dst[m*16384 + (tc*32 + c)*128 + (tr*32 + r)] = __float2bfloat16(t[r*33 + c]);
    }
}

// ---------------- Prep: temporal tables + router weight tile ----------------
// Benc  f16 [128n][128k]: n<64 -> u_re col e: [Er[k][e] | -Ei[k-64][e]]
//                         n>=64 -> u_im col e: [Ei[k][e] |  Er[k-64][e]]
// BdecX f16 [64n][256k] : k and k+128 hold the SAME value (hi/lo split accumulation)
//                         base (k<128): [Dr[k][d] | -Di[k-64][d]]
// coefG float4[(b*16+t)*64+e] = (a_re, a_im, f_re, f_im);  nscG[b*16+t] = 0.01*sqrt(dt)
// rwB   bf16 [16n][128k]: n<4 -> router_w[k][n], rest zero (router as MFMA B-operand)
__global__ __launch_bounds__(256) void k_prep_enc(
    const float* __restrict__ encr, const float* __restrict__ enci,
    const float* __restrict__ decr, const float* __restrict__ deci,
    const float* __restrict__ dt,
    const float* __restrict__ lamr, const float* __restrict__ lami,
    const float* __restrict__ rw,
    _Float16* __restrict__ Benc, _Float16* __restrict__ BdecX,
    float4* __restrict__ coefG, float* __restrict__ nscG,
    __hip_bfloat16* __restrict__ rwB)
{
    int idx = blockIdx.x*256 + threadIdx.x;
    if (idx < 16384) {
        int n = idx >> 7, k = idx & 127;
        int e = n & 63, d = k & 63;
        float v;
        if (n < 64) v = (k < 64) ? encr[d*64 + e] : -enci[d*64 + e];
        else        v = (k < 64) ? enci[d*64 + e] :  encr[d*64 + e];
        Benc[idx] = (_Float16)v;
    }
    if (idx < 16384) {
        int n = idx >> 8, k = idx & 255;
        int kk = k & 127;
        int e = kk & 63;
        float v = (kk < 64) ? decr[e*64 + n] : -deci[e*64 + n];
        BdecX[idx] = (_Float16)v;
    }
    if (idx < 2048) {
        int bt = idx >> 6, e = idx & 63;
        float dtv = dt[bt];
        float lr = lamr[e];
        float sp = (lr > 20.f) ? lr : log1pf(expf(lr));
        float lre = -sp, lim = lami[e];
        float inv = 1.f / (lre*lre + lim*lim);
        float ex = expf(lre*dtv);
        float sn, cs; sincosf(lim*dtv, &sn, &cs);
        float ar = ex*cs, ai = ex*sn;
        float fr = ((ar - 1.f)*lre + ai*lim)*inv;
        float fi = (ai*lre - (ar - 1.f)*lim)*inv;
        coefG[idx] = make_float4(ar, ai, fr, fi);
    }
    if (idx < 2048) {
        int n = idx >> 7, k = idx & 127;
        float v = (n < 4) ? rw[k*4 + n] : 0.f;
        rwB[idx] = __float2bfloat16(v);
    }
    if (idx < 32) nscG[idx] = 0.01f * sqrtf(dt[idx]);
}

// ---------------- Stage 1 (FUSED): spatial complex LayerNorm + 3x3 conv MFMA + residual -------
// Phase A replaces the separate k_ln_s kernel: for each of the 3 halo rows, wave q loads
// channel block c in [32q, 32q+32) for all 64 px (coalesced 256B per load, values in 32 VGPRs),
// per-px mean/var via LDS partials, then normalize + bf16-pack + ds_write_b128 into inrow.
// Halo rows are LN'd redundantly by 3 h-blocks; x (134 MB) is L3-resident so re-reads are cheap.
// Saves the 67 MB bufB round-trip and an entire kernel pass. MFMA section + epilogue unchanged.
__global__ __launch_bounds__(256) void k_conv_mfma(
    const float* __restrict__ xr, const float* __restrict__ xi,
    const float* __restrict__ lw, const float* __restrict__ lb,
    const __hip_bfloat16* __restrict__ wB,
    const float* __restrict__ cb,
    float* __restrict__ x1)
{
    __shared__ __align__(16) short inrow[3*66*136];   // 53856 B
    __shared__ float ps[64*4];
    __shared__ float ps2[64*4];
    __shared__ float mu_s[64];
    __shared__ float rs_s[64];
    __shared__ float lwS[128];
    __shared__ float lbS[128];
    int bt = blockIdx.x, h = blockIdx.y;
    int tid = threadIdx.x;
    int wl = tid & 63;   // pixel lane (W index within the 64-px row)
    int q  = tid >> 6;   // wave id = channel block [32q, 32q+32)

    if (tid < 128) { lwS[tid] = lw[tid]; lbS[tid] = lb[tid]; }
    if (tid >= 128 && tid < 224) {   // zero the px=0 / px=65 pad columns (SAME conv)
        int t = tid - 128;
        int r = t / 32, t2 = t & 31;
        int px = (t2 & 1) ? 65 : 0;
        int j = t2 >> 1;
        *(float4*)&inrow[(r*66 + px)*136 + j*8] = make_float4(0.f,0.f,0.f,0.f);
    }
    // lwS/pads are fenced by the first __syncthreads below.

    const float* srcb = (q < 2) ? xr : xi;
    int dbase = (q & 1) * 32;           // d = (q&1)*32 + k for c = q*32 + k
    for (int r = 0; r < 3; r++) {
        int gh = h + r - 1;
        bool ok = ((unsigned)gh < 64u);  // block-uniform: barriers below are safe
        float v[32];
        if (ok) {
            float s = 0.f, s2 = 0.f;
            const float* base = &srcb[((size_t)(bt*64 + dbase))*HW + gh*64 + wl];
            #pragma unroll
            for (int k = 0; k < 32; k++) {
                float vv = base[(size_t)k*HW];
                v[k] = vv; s += vv; s2 += vv*vv;
            }
            ps [wl*4 + q] = s;
            ps2[wl*4 + q] = s2;
        }
        __syncthreads();
        if (ok && tid < 64) {
            float ss = ps[tid*4+0]+ps[tid*4+1]+ps[tid*4+2]+ps[tid*4+3];
            float qq = ps2[tid*4+0]+ps2[tid*4+1]+ps2[tid*4+2]+ps2[tid*4+3];
            float mu = ss * 0.0078125f;
            float var = qq * 0.0078125f - mu*mu;
            mu_s[tid] = mu;
            rs_s[tid] = rsqrtf(var + 1e-5f);
        }
        __syncthreads();
        short* drow = &inrow[(r*66 + wl + 1)*136 + q*32];
        if (ok) {
            float mu = mu_s[wl], rs = rs_s[wl];
            #pragma unroll
            for (int j = 0; j < 4; j++) {
                union { __hip_bfloat16 hh[8]; float4 f; } u;
                #pragma unroll
                for (int k = 0; k < 8; k++) {
                    int c = q*32 + j*8 + k;
                    u.hh[k] = __float2bfloat16((v[j*8+k] - mu)*rs*lwS[c] + lbS[c]);
                }
                *(float4*)&drow[j*8] = u.f;
            }
        } else {
            float4 z = make_float4(0.f,0.f,0.f,0.f);
            #pragma unroll
            for (int j = 0; j < 4; j++) *(float4*)&drow[j*8] = z;
        }
    }
    __syncthreads();

    int wv = tid >> 6, l = tid & 63, lm = l & 15, qq2 = l >> 4;
    int n0 = wv * 32;
    f32x4 acc[4][2];
    #pragma unroll
    for (int mi = 0; mi < 4; mi++)
        #pragma unroll
        for (int ni = 0; ni < 2; ni++)
            acc[mi][ni] = (f32x4){0.f,0.f,0.f,0.f};

    for (int p = 0; p < 9; p++) {
        int kh = p / 3, kw = p - kh*3;
        const __hip_bfloat16* wp = wB + p*16384;
        int abase = (kh*66 + kw)*136;
        #pragma unroll
        for (int ks = 0; ks < 4; ks++) {
            int ko = ks*32 + qq2*8;
            bf16x8 b0 = *(const bf16x8*)(wp + (n0 + lm)*128 + ko);
            bf16x8 b1 = *(const bf16x8*)(wp + (n0 + 16 + lm)*128 + ko);
            #pragma unroll
            for (int mi = 0; mi < 4; mi++) {
                bf16x8 a = *(const bf16x8*)&inrow[abase + (mi*16 + lm)*136 + ko];
                acc[mi][0] = MFMA_BF16(a, b0, acc[mi][0]);
                acc[mi][1] = MFMA_BF16(a, b1, acc[mi][1]);
            }
        }
    }
    #pragma unroll
    for (int ni = 0; ni < 2; ni++) {
        int oc = n0 + ni*16 + lm;
        float bias = cb[oc];
        const float* rsp = (oc < 64) ? xr : xi;
        const float* rbase = &rsp[(bt*64 + (oc & 63))*HW + h*64];
        #pragma unroll
        for (int mi = 0; mi < 4; mi++) {
            #pragma unroll
            for (int r = 0; r < 4; r++) {
                int w = mi*16 + qq2*4 + r;
                x1[(size_t)(bt*HW + h*64 + w)*128 + oc] = acc[mi][ni][r] + bias + rbase[w];
            }
        }
    }
}

// ---------------- Stage 2: temporal via MFMA, f16 + hi/lo-split decode ----------------
// block = 128 thr / 2 waves, 4 pixels. A-tile 64 rows = (n_local,t), pitch 264:
// cols 0..127 = z then h_hi [re|im]; cols 128..255 = h_lo [re|im].
// GEMM1 (encode, K=128) -> in-fragment complex scan -> h hi/lo to tile -> GEMM2 (decode, K=256).
__global__ __launch_bounds__(128) void k_temporal_mfma(
    float* xio,
    const float* __restrict__ lw, const float* __restrict__ lb,
    const float* __restrict__ sbr, const float* __restrict__ sbi,
    const _Float16* __restrict__ Benc, const _Float16* __restrict__ BdecX,
    const float4* __restrict__ coefG, const float* __restrict__ nscG,
    const float* __restrict__ nzr, const float* __restrict__ nzi)
{
    __shared__ __align__(16) short At[64*TP];   // 33792 B
    int n0  = blockIdx.x * 4;
    int b   = n0 >> 12;
    int hw0 = n0 & 4095;
    int tid = threadIdx.x;

    // LN: 2 threads per row (row = n_local*16 + t), f16 into A-tile cols 0..127
    {
        int row = tid >> 1, half = tid & 1;
        int nl = row >> 4, t = row & 15;
        const float4* src = (const float4*)&xio[((size_t)((b*16 + t)*HW) + hw0 + nl)*128 + half*64];
        float4 v[16];
        float s = 0.f, s2 = 0.f;
        #pragma unroll
        for (int j = 0; j < 16; j++) {
            v[j] = src[j];
            s  += v[j].x + v[j].y + v[j].z + v[j].w;
            s2 += v[j].x*v[j].x + v[j].y*v[j].y + v[j].z*v[j].z + v[j].w*v[j].w;
        }
        s  += __shfl_xor(s, 1, 64);
        s2 += __shfl_xor(s2, 1, 64);
        float mu  = s * 0.0078125f;
        float var = s2 * 0.0078125f - mu*mu;
        float rsq = rsqrtf(var + 1e-5f);
        const float4* lw4 = (const float4*)(lw + half*64);
        const float4* lb4 = (const float4*)(lb + half*64);
        short* dstrow = &At[row*TP + half*64];
        #pragma unroll
        for (int j = 0; j < 16; j++) {
            float4 wv4 = lw4[j], bv = lb4[j];
            union { _Float16 h[4]; float2 f; } u;
            u.h[0] = (_Float16)((v[j].x - mu)*rsq*wv4.x + bv.x);
            u.h[1] = (_Float16)((v[j].y - mu)*rsq*wv4.y + bv.y);
            u.h[2] = (_Float16)((v[j].z - mu)*rsq*wv4.z + bv.z);
            u.h[3] = (_Float16)((v[j].w - mu)*rsq*wv4.w + bv.w);
            *(float2*)(dstrow + j*4) = u.f;
        }
    }
    __syncthreads();   // coef/LN cross-wave publish; tile rows are wave-private below

    int wv = tid >> 6, l = tid & 63, lm = l & 15, q = l >> 4;

    // GEMM1: u_pre = z @ Benc  (ni<4 = re cols, ni+4 = im cols)
    f32x4 acc[2][8];
    #pragma unroll
    for (int mi = 0; mi < 2; mi++)
        #pragma unroll
        for (int ni = 0; ni < 8; ni++)
            acc[mi][ni] = (f32x4){0.f,0.f,0.f,0.f};
    #pragma unroll
    for (int ks = 0; ks < 4; ks++) {
        int ko = ks*32 + q*8;
        f16x8 a0 = *(const f16x8*)&At[((2*wv+0)*16 + lm)*TP + ko];
        f16x8 a1 = *(const f16x8*)&At[((2*wv+1)*16 + lm)*TP + ko];
        #pragma unroll
        for (int ni = 0; ni < 8; ni++) {
            f16x8 bb = *(const f16x8*)(Benc + (ni*16 + lm)*128 + ko);
            acc[0][ni] = MFMA_F16(a0, bb, acc[0][ni]);
            acc[1][ni] = MFMA_F16(a1, bb, acc[1][ni]);
        }
    }

    // in-fragment complex scan (coef from global table); write h hi/lo into wave rows
    int btbase = b*16;
    #pragma unroll
    for (int ni = 0; ni < 4; ni++) {
        int e = ni*16 + lm;
        float br = sbr[e], bi = sbi[e];
        float4 cf[4]; float ns[4];
        #pragma unroll
        for (int r = 0; r < 4; r++) {
            int t = q*4 + r;
            cf[r] = coefG[(btbase + t)*64 + e];
            ns[r] = nscG[btbase + t];
        }
        #pragma unroll
        for (int mi = 0; mi < 2; mi++) {
            int nl = 2*wv + mi;
            int ng = n0 + nl;
            float nrv[4], niv[4];
            #pragma unroll
            for (int r = 0; r < 4; r++) {
                int off = (ng*16 + q*4 + r)*64 + e;
                nrv[r] = nzr[off];
                niv[r] = nzi[off];
            }
            float hr = 0.f, hi = 0.f, Apr = 1.f, Api = 0.f;
            float hrs[4], his[4], Aprs[4], Apis[4];
            #pragma unroll
            for (int r = 0; r < 4; r++) {
                float Sr = acc[mi][ni][r] + br;
                float Si = acc[mi][ni+4][r] + bi;
                float ur = Sr*cf[r].z - Si*cf[r].w + ns[r]*nrv[r];
                float ui = Sr*cf[r].w + Si*cf[r].z + ns[r]*niv[r];
                if (r == 0) { hr = ur; hi = ui; Apr = cf[0].x; Api = cf[0].y; }
                else {
                    float tr = cf[r].x*hr - cf[r].y*hi + ur;
                    float ti = cf[r].x*hi + cf[r].y*hr + ui;
                    hr = tr; hi = ti;
                    tr = cf[r].x*Apr - cf[r].y*Api;
                    ti = cf[r].x*Api + cf[r].y*Apr;
                    Apr = tr; Api = ti;
                }
                hrs[r] = hr; his[r] = hi; Aprs[r] = Apr; Apis[r] = Api;
            }
            // quad-prefix over segments (A,H): h_out = H + A*h_in
            float Ar = Apr, Ai = Api, Hr = hr, Hi = hi;
            #pragma unroll
            for (int off = 16; off <= 32; off <<= 1) {
                float pAr = __shfl_up(Ar, off, 64);
                float pAi = __shfl_up(Ai, off, 64);
                float pHr = __shfl_up(Hr, off, 64);
                float pHi = __shfl_up(Hi, off, 64);
                if (l >= off) {
                    Hr = Hr + Ar*pHr - Ai*pHi;
                    Hi = Hi + Ar*pHi + Ai*pHr;
                    float tAr = Ar*pAr - Ai*pAi;
                    float tAi = Ar*pAi + Ai*pAr;
                    Ar = tAr; Ai = tAi;
                }
            }
            float gr = __shfl_up(Hr, 16, 64);
            float gi = __shfl_up(Hi, 16, 64);
            if (q == 0) { gr = 0.f; gi = 0.f; }
            #pragma unroll
            for (int r = 0; r < 4; r++) {
                float fhr = hrs[r] + Aprs[r]*gr - Apis[r]*gi;
                float fhi = his[r] + Aprs[r]*gi + Apis[r]*gr;
                int row = nl*16 + q*4 + r;
                _Float16 hrh = (_Float16)fhr;
                _Float16 hih = (_Float16)fhi;
                *(_Float16*)&At[row*TP + e]        = hrh;
                *(_Float16*)&At[row*TP + 64 + e]   = hih;
                *(_Float16*)&At[row*TP + 128 + e]  = (_Float16)(fhr - (float)hrh);
                *(_Float16*)&At[row*TP + 192 + e]  = (_Float16)(fhi - (float)hih);
            }
        }
    }

    // GEMM2: drift = (h_hi + h_lo) @ BdecX  (K=256, duplicated weights)
    f32x4 acc2[2][4];
    #pragma unroll
    for (int mi = 0; mi < 2; mi++)
        #pragma unroll
        for (int ni = 0; ni < 4; ni++)
            acc2[mi][ni] = (f32x4){0.f,0.f,0.f,0.f};
    #pragma unroll
    for (int ks = 0; ks < 8; ks++) {
        int ko = ks*32 + q*8;
        f16x8 a0 = *(const f16x8*)&At[((2*wv+0)*16 + lm)*TP + ko];
        f16x8 a1 = *(const f16x8*)&At[((2*wv+1)*16 + lm)*TP + ko];
        #pragma unroll
        for (int ni = 0; ni < 4; ni++) {
            f16x8 bb = *(const f16x8*)(BdecX + (ni*16 + lm)*256 + ko);
            acc2[0][ni] = MFMA_F16(a0, bb, acc2[0][ni]);
            acc2[1][ni] = MFMA_F16(a1, bb, acc2[1][ni]);
        }
    }

    // epilogue: xio.re += drift (in place, re-half only)
    #pragma unroll
    for (int mi = 0; mi < 2; mi++) {
        int nl = 2*wv + mi;
        #pragma unroll
        for (int ni = 0; ni < 4; ni++) {
            int d = ni*16 + lm;
            #pragma unroll
            for (int r = 0; r < 4; r++) {
                int t = q*4 + r;
                size_t idx = ((size_t)((b*16 + t)*HW) + hw0 + nl)*128 + d;
                xio[idx] = xio[idx] + acc2[mi][ni][r];
            }
        }
    }
}

// ---------------- Stage 3: MoE FFN via MFMA (measured-best 114 us structure) ----
// 256 thr / 64 tokens / 35.8 KB LDS. Column-split: wave owns a 32-col weight strip.
__global__ __launch_bounds__(256) void k_moe_mfma(
    const float* __restrict__ xio,
    float* __restrict__ outp,
    const __hip_bfloat16* __restrict__ rwB, const float* __restrict__ rb,
    const __hip_bfloat16* __restrict__ w1b, const float* __restrict__ b1,
    const __hip_bfloat16* __restrict__ w2b, const float* __restrict__ b2)
{
    __shared__ __align__(16) short smem[2*64*136];   // tokA | hidA; reused as fp32 tile 64x129
    __shared__ float gates[256];
    short* tokA = smem;
    short* hidA = smem + 64*136;
    float* tile = (float*)smem;
    int tok0 = blockIdx.x * 64;
    int tid = threadIdx.x;
    for (int lsd = tid; lsd < 2048; lsd += 256) {
        int t = lsd >> 5, j = lsd & 31;
        float4 v = *(const float4*)&xio[(size_t)(tok0 + t)*128 + j*4];
        union { __hip_bfloat16 h[4]; float2 f; } u;
        u.h[0] = __float2bfloat16(v.x);
        u.h[1] = __float2bfloat16(v.y);
        u.h[2] = __float2bfloat16(v.z);
        u.h[3] = __float2bfloat16(v.w);
        *(float2*)&tokA[t*136 + j*4] = u.f;
    }
    __syncthreads();

    int wv = tid >> 6, l = tid & 63, lm = l & 15, q = l >> 4;
    int n0 = wv * 32;

    // Router via MFMA: wave wv computes logits for token rows [n0, n0+32).
    // gates published to other waves by the post-GELU barrier of expert 0.
    {
        f32x4 racc[2];
        racc[0] = (f32x4){0.f,0.f,0.f,0.f};
        racc[1] = (f32x4){0.f,0.f,0.f,0.f};
        #pragma unroll
        for (int ks = 0; ks < 4; ks++) {
            int ko = ks*32 + q*8;
            bf16x8 bb = *(const bf16x8*)(rwB + lm*128 + ko);
            bf16x8 a0 = *(const bf16x8*)&tokA[(n0 + lm)*136 + ko];
            bf16x8 a1 = *(const bf16x8*)&tokA[(n0 + 16 + lm)*136 + ko];
            racc[0] = MFMA_BF16(a0, bb, racc[0]);
            racc[1] = MFMA_BF16(a1, bb, racc[1]);
        }
        float rb_l = rb[lm & 3];
        #pragma unroll
        for (int mi = 0; mi < 2; mi++) {
            #pragma unroll
            for (int r = 0; r < 4; r++) {
                float g = racc[mi][r] + rb_l;
                float mx = fmaxf(g, __shfl_xor(g, 1, 64));
                mx = fmaxf(mx, __shfl_xor(mx, 2, 64));
                float ev = __expf(g - mx);
                float sv = ev + __shfl_xor(ev, 1, 64);
                sv += __shfl_xor(sv, 2, 64);
                if (lm < 4)
                    gates[(n0 + mi*16 + q*4 + r)*4 + lm] = ev * __builtin_amdgcn_rcpf(sv);
            }
        }
    }

    f32x4 outa[4][2];
    #pragma unroll
    for (int mi = 0; mi < 4; mi++)
        #pragma unroll
        for (int ni = 0; ni < 2; ni++)
            outa[mi][ni] = (f32x4){0.f,0.f,0.f,0.f};

    for (int e = 0; e < 4; e++) {
        // GEMM1: hid[all 64 rows][n0..n0+32) = tok @ w1[e] strip  (reads tokA only)
        f32x4 acc1[4][2];
        #pragma unroll
        for (int mi = 0; mi < 4; mi++)
            #pragma unroll
            for (int ni = 0; ni < 2; ni++)
                acc1[mi][ni] = (f32x4){0.f,0.f,0.f,0.f};
        const __hip_bfloat16* wp1 = w1b + e*16384;
        #pragma unroll
        for (int ks = 0; ks < 4; ks++) {
            int ko = ks*32 + q*8;
            bf16x8 b0  = *(const bf16x8*)(wp1 + (n0 + lm)*128 + ko);
            bf16x8 b1v = *(const bf16x8*)(wp1 + (n0 + 16 + lm)*128 + ko);
            #pragma unroll
            for (int mi = 0; mi < 4; mi++) {
                bf16x8 a = *(const bf16x8*)&tokA[(mi*16 + lm)*136 + ko];
                acc1[mi][0] = MFMA_BF16(a, b0,  acc1[mi][0]);
                acc1[mi][1] = MFMA_BF16(a, b1v, acc1[mi][1]);
            }
        }
        // GELU -> hidA own cols (writes fenced vs GEMM2(e-1) by loop-end barrier)
        #pragma unroll
        for (int ni = 0; ni < 2; ni++) {
            int hcol = n0 + ni*16 + lm;
            float bb = b1[e*128 + hcol];
            #pragma unroll
            for (int mi = 0; mi < 4; mi++) {
                #pragma unroll
                for (int r = 0; r < 4; r++) {
                    float hv = gelu_f(acc1[mi][ni][r] + bb);
                    int m = mi*16 + q*4 + r;
                    *(__hip_bfloat16*)&hidA[m*136 + hcol] = __float2bfloat16(hv);
                }
            }
        }
        __syncthreads();   // publish hidA (and gates on e=0)
        // GEMM2: delta[all rows][n0..n0+32) = hid @ w2[e] strip (contracts all 128 h-cols)
        f32x4 acc2[4][2];
        #pragma unroll
        for (int mi = 0; mi < 4; mi++)
            #pragma unroll
            for (int ni = 0; ni < 2; ni++)
                acc2[mi][ni] = (f32x4){0.f,0.f,0.f,0.f};
        const __hip_bfloat16* wp2 = w2b + e*16384;
        #pragma unroll
        for (int ks = 0; ks < 4; ks++) {
            int ko = ks*32 + q*8;
            bf16x8 b0  = *(const bf16x8*)(wp2 + (n0 + lm)*128 + ko);
            bf16x8 b1v = *(const bf16x8*)(wp2 + (n0 + 16 + lm)*128 + ko);
            #pragma unroll
            for (int mi = 0; mi < 4; mi++) {
                bf16x8 a = *(const bf16x8*)&hidA[(mi*16 + lm)*136 + ko];
                acc2[mi][0] = MFMA_BF16(a, b0,  acc2[mi][0]);
                acc2[mi][1] = MFMA_BF16(a, b1v, acc2[mi][1]);
            }
        }
        #pragma unroll
        for (int ni = 0; ni < 2; ni++) {
            int ocol = n0 + ni*16 + lm;
            float bb = b2[e*128 + ocol];
            #pragma unroll
            for (int mi = 0; mi < 4; mi++) {
                #pragma unroll
                for (int r = 0; r < 4; r++) {
                    int m = mi*16 + q*4 + r;
                    float g = gates[m*4 + e];
                    outa[mi][ni][r] += g * (acc2[mi][ni][r] + bb);
                }
            }
        }
        __syncthreads();   // hidA readers done before next expert's GELU overwrites
    }

    // final = residual + delta -> LDS tile (pitch 129) -> native-layout store
    #pragma unroll
    for (int ni = 0; ni < 2; ni++) {
        int col = n0 + ni*16 + lm;
        #pragma unroll
        for (int mi = 0; mi < 4; mi++) {
            #pragma unroll
            for (int r = 0; r < 4; r++) {
                int m = mi*16 + q*4 + r;
                tile[m*129 + col] = xio[(size_t)(tok0 + m)*128 + col] + outa[mi][ni][r];
            }
        }
    }
    __syncthreads();
    int bt = tok0 >> 12;
    int hw0 = tok0 & 4095;
    for (int lid = tid; lid < 8192; lid += 256) {
        int c = lid >> 6, m = lid & 63;
        int p = c >> 6, d = c & 63;
        outp[((size_t)((p*32 + bt)*64 + d))*HW + hw0 + m] = tile[m*129 + c];
    }
}

extern "C" void kernel_launch(void* const* d_in, const int* in_sizes, int n_in,
                              void* d_out, int out_size, void* d_ws, size_t ws_size,
                              hipStream_t stream)
{
    const float* x_real = (const float*)d_in[0];
    const float* x_imag = (const float*)d_in[1];
    const float* dt     = (const float*)d_in[2];
    const float* nzr    = (const float*)d_in[3];
    const float* nzi    = (const float*)d_in[4];
    const float* ln_s_w = (const float*)d_in[5];
    const float* ln_s_b = (const float*)d_in[6];
    const float* conv_w = (const float*)d_in[7];
    const float* conv_b = (const float*)d_in[8];
    const float* ln_t_w = (const float*)d_in[9];
    const float* ln_t_b = (const float*)d_in[10];
    const float* lam_re = (const float*)d_in[11];
    const float* lam_im = (const float*)d_in[12];
    const float* sbr    = (const float*)d_in[13];
    const float* sbi    = (const float*)d_in[14];
    const float* enc_re = (const float*)d_in[15];
    const float* enc_im = (const float*)d_in[16];
    const float* dec_re = (const float*)d_in[17];
    const float* dec_im = (const float*)d_in[18];
    const float* rw     = (const float*)d_in[19];
    const float* rb     = (const float*)d_in[20];
    const float* w1     = (const float*)d_in[21];
    const float* b1     = (const float*)d_in[22];
    const float* w2     = (const float*)d_in[23];
    const float* b2     = (const float*)d_in[24];

    char* ws = (char*)d_ws;
    float* bufA = (float*)ws;                                              // 64 MiB fp32 layout-A
    __hip_bfloat16* wBc  = (__hip_bfloat16*)(ws + (size_t)96*1024*1024);   // conv weights [9][oc][ic]
    __hip_bfloat16* w1b  = wBc + 9*16384;
    __hip_bfloat16* w2b  = w1b + 4*16384;
    _Float16* Benc  = (_Float16*)(w2b + 4*16384);                          // [128][128] f16
    _Float16* BdecX = Benc + 16384;                                        // [64][256] f16
    float4* coefG = (float4*)(BdecX + 16384);                              // [2048]
    float* nscG   = (float*)(coefG + 2048);                                // [32]
    __hip_bfloat16* rwB = (__hip_bfloat16*)(nscG + 32);                    // [16][128] bf16 router
    float* outp = (float*)d_out;

    k_prep_t  <<<dim3(9,16), 256, 0, stream>>>(conv_w, wBc);
    k_prep_t  <<<dim3(4,16), 256, 0, stream>>>(w1, w1b);
    k_prep_t  <<<dim3(4,16), 256, 0, stream>>>(w2, w2b);
    k_prep_enc<<<64,         256, 0, stream>>>(enc_re, enc_im, dec_re, dec_im,
                                               dt, lam_re, lam_im, rw,
                                               Benc, BdecX, coefG, nscG, rwB);

    k_conv_mfma    <<<dim3(32,64), 256, 0, stream>>>(x_real, x_imag, ln_s_w, ln_s_b,
                                                     wBc, conv_b, bufA);
    k_temporal_mfma<<<2048,        128, 0, stream>>>(bufA, ln_t_w, ln_t_b, sbr, sbi,
                                                     Benc, BdecX, coefG, nscG, nzr, nzi);
    k_moe_mfma     <<<2048,        256, 0, stream>>>(bufA, outp, rwB, rb, w1b, b1, w2b, b2);
}

// Round 12
// 470.272 us; speedup vs baseline: 1.5097x; 1.0029x over previous
//
#include <hip/hip_runtime.h>
#include <hip/hip_bf16.h>
#include <math.h>

#define HW 4096
#define TP 264   // temporal A-tile pitch in halves: 528 B row stride == 4 mod 32 banks (2-way, free)

typedef __attribute__((ext_vector_type(8))) short bf16x8;
typedef _Float16 f16x8 __attribute__((ext_vector_type(8)));
typedef __attribute__((ext_vector_type(4))) float f32x4;

#define MFMA_BF16(a, b, c) __builtin_amdgcn_mfma_f32_16x16x32_bf16((a), (b), (c), 0, 0, 0)
#define MFMA_F16(a, b, c)  __builtin_amdgcn_mfma_f32_16x16x32_f16((a), (b), (c), 0, 0, 0)

static __device__ __forceinline__ float gelu_f(float xv) {
    // tanh-gelu via sigmoid identity: 0.5x(1+tanh(t)) = x*e/(e+1), e=exp(2t)
    float x2 = xv*xv;
    float t2 = xv*(1.5957691216057308f + 0.07135481627260025f*x2);
    float ee = __expf(t2);
    return xv*(1.f - __builtin_amdgcn_rcpf(ee + 1.f));
}

// ---------------- Prep: fp32 [nmat][128][128] -> bf16 [nmat][128][128] transposed ----------------
__global__ __launch_bounds__(256) void k_prep_t(
    const float* __restrict__ src, __hip_bfloat16* __restrict__ dst)
{
    __shared__ float t[32*33];
    int m  = blockIdx.x;
    int tr = blockIdx.y >> 2, tc = blockIdx.y & 3;
    int tid = threadIdx.x;
    for (int l = tid; l < 1024; l += 256) {
        int r = l >> 5, c = l & 31;
        t[r*33 + c] = src[m*16384 + (tr*32 + r)*128 + (tc*32 + c)];
    }
    __syncthreads();
    for (int l = tid; l < 1024; l += 256) {
        int c = l >> 5, r = l & 31;
        dst[m*16384 + (tc*32 + c)*128 + (tr*32 + r)] = __float2bfloat16(t[r*33 + c]);
    }
}

// ---------------- Prep: temporal tables + router weight tile ----------------
// Benc  f16 [128n][128k]: n<64 -> u_re col e: [Er[k][e] | -Ei[k-64][e]]
//                         n>=64 -> u_im col e: [Ei[k][e] |  Er[k-64][e]]
// BdecX f16 [64n][256k] : k and k+128 hold the SAME value (hi/lo split accumulation)
//                         base (k<128): [Dr[k][d] | -Di[k-64][d]]
// coefG float4[(b*16+t)*64+e] = (a_re, a_im, f_re, f_im);  nscG[b*16+t] = 0.01*sqrt(dt)
// rwB   bf16 [16n][128k]: n<4 -> router_w[k][n], rest zero (router as MFMA B-operand)
__global__ __launch_bounds__(256) void k_prep_enc(
    const float* __restrict__ encr, const float* __restrict__ enci,
    const float* __restrict__ decr, const float* __restrict__ deci,
    const float* __restrict__ dt,
    const float* __restrict__ lamr, const float* __restrict__ lami,
    const float* __restrict__ rw,
    _Float16* __restrict__ Benc, _Float16* __restrict__ BdecX,
    float4* __restrict__ coefG, float* __restrict__ nscG,
    __hip_bfloat16* __restrict__ rwB)
{
    int idx = blockIdx.x*256 + threadIdx.x;
    if (idx < 16384) {
        int n = idx >> 7, k = idx & 127;
        int e = n & 63, d = k & 63;
        float v;
        if (n < 64) v = (k < 64) ? encr[d*64 + e] : -enci[d*64 + e];
        else        v = (k < 64) ? enci[d*64 + e] :  encr[d*64 + e];
        Benc[idx] = (_Float16)v;
    }
    if (idx < 16384) {
        int n = idx >> 8, k = idx & 255;
        int kk = k & 127;
        int e = kk & 63;
        float v = (kk < 64) ? decr[e*64 + n] : -deci[e*64 + n];
        BdecX[idx] = (_Float16)v;
    }
    if (idx < 2048) {
        int bt = idx >> 6, e = idx & 63;
        float dtv = dt[bt];
        float lr = lamr[e];
        float sp = (lr > 20.f) ? lr : log1pf(expf(lr));
        float lre = -sp, lim = lami[e];
        float inv = 1.f / (lre*lre + lim*lim);
        float ex = expf(lre*dtv);
        float sn, cs; sincosf(lim*dtv, &sn, &cs);
        float ar = ex*cs, ai = ex*sn;
        float fr = ((ar - 1.f)*lre + ai*lim)*inv;
        float fi = (ai*lre - (ar - 1.f)*lim)*inv;
        coefG[idx] = make_float4(ar, ai, fr, fi);
    }
    if (idx < 2048) {
        int n = idx >> 7, k = idx & 127;
        float v = (n < 4) ? rw[k*4 + n] : 0.f;
        rwB[idx] = __float2bfloat16(v);
    }
    if (idx < 32) nscG[idx] = 0.01f * sqrtf(dt[idx]);
}

// ---------------- Stage 1 (FUSED): spatial complex LayerNorm + 3x3 conv MFMA + residual -------
// Phase A: wave q LNs channel block [32q,32q+32) of each halo row into the A-tile.
// A-tile pitch cut 136 -> 128 halves (LDS 57.9 -> 54.3 KB => 3 blocks/CU, was the occupancy
// limiter). Pitch-128 rows alias to one bank group (256B = 0 mod 128), so all 16B LDS accesses
// use the XOR swizzle half_off ^ ((row&7)<<3) -- writers (LN pack, zero-pad) and readers
// (MFMA A-frag) share the same flattened-row key, so the permutation matches on both sides.
// Also fixes the LN ds_write pattern from 16-way to 2-way conflicts.
__global__ __launch_bounds__(256) void k_conv_mfma(
    const float* __restrict__ xr, const float* __restrict__ xi,
    const float* __restrict__ lw, const float* __restrict__ lb,
    const __hip_bfloat16* __restrict__ wB,
    const float* __restrict__ cb,
    float* __restrict__ x1)
{
    __shared__ __align__(16) short inrow[3*66*128];   // 50688 B (+3584 stats = 54272 total)
    __shared__ float ps[64*4];
    __shared__ float ps2[64*4];
    __shared__ float mu_s[64];
    __shared__ float rs_s[64];
    __shared__ float lwS[128];
    __shared__ float lbS[128];
    int bt = blockIdx.x, h = blockIdx.y;
    int tid = threadIdx.x;
    int wl = tid & 63;   // pixel lane (W index within the 64-px row)
    int q  = tid >> 6;   // wave id = channel block [32q, 32q+32)

    if (tid < 128) { lwS[tid] = lw[tid]; lbS[tid] = lb[tid]; }
    if (tid >= 128 && tid < 224) {   // zero the px=0 / px=65 pad columns (SAME conv)
        int t = tid - 128;
        int r = t / 32, t2 = t & 31;
        int px = (t2 & 1) ? 65 : 0;
        int j = t2 >> 1;
        int row = r*66 + px;
        *(float4*)&inrow[row*128 + ((j*8) ^ ((row & 7) << 3))] = make_float4(0.f,0.f,0.f,0.f);
    }
    // lwS/pads are fenced by the first __syncthreads below.

    const float* srcb = (q < 2) ? xr : xi;
    int dbase = (q & 1) * 32;           // d = (q&1)*32 + k for c = q*32 + k
    for (int r = 0; r < 3; r++) {
        int gh = h + r - 1;
        bool ok = ((unsigned)gh < 64u);  // block-uniform: barriers below are safe
        float v[32];
        if (ok) {
            float s = 0.f, s2 = 0.f;
            const float* base = &srcb[((size_t)(bt*64 + dbase))*HW + gh*64 + wl];
            #pragma unroll
            for (int k = 0; k < 32; k++) {
                float vv = base[(size_t)k*HW];
                v[k] = vv; s += vv; s2 += vv*vv;
            }
            ps [wl*4 + q] = s;
            ps2[wl*4 + q] = s2;
        }
        __syncthreads();
        if (ok && tid < 64) {
            float ss = ps[tid*4+0]+ps[tid*4+1]+ps[tid*4+2]+ps[tid*4+3];
            float qq = ps2[tid*4+0]+ps2[tid*4+1]+ps2[tid*4+2]+ps2[tid*4+3];
            float mu = ss * 0.0078125f;
            float var = qq * 0.0078125f - mu*mu;
            mu_s[tid] = mu;
            rs_s[tid] = rsqrtf(var + 1e-5f);
        }
        __syncthreads();
        int row = r*66 + wl + 1;
        short* drowbase = &inrow[row*128];
        int key = (row & 7) << 3;
        if (ok) {
            float mu = mu_s[wl], rs = rs_s[wl];
            #pragma unroll
            for (int j = 0; j < 4; j++) {
                union { __hip_bfloat16 hh[8]; float4 f; } u;
                #pragma unroll
                for (int k = 0; k < 8; k++) {
                    int c = q*32 + j*8 + k;
                    u.hh[k] = __float2bfloat16((v[j*8+k] - mu)*rs*lwS[c] + lbS[c]);
                }
                *(float4*)&drowbase[(q*32 + j*8) ^ key] = u.f;
            }
        } else {
            float4 z = make_float4(0.f,0.f,0.f,0.f);
            #pragma unroll
            for (int j = 0; j < 4; j++) *(float4*)&drowbase[(q*32 + j*8) ^ key] = z;
        }
    }
    __syncthreads();

    int wv = tid >> 6, l = tid & 63, lm = l & 15, qq2 = l >> 4;
    int n0 = wv * 32;
    f32x4 acc[4][2];
    #pragma unroll
    for (int mi = 0; mi < 4; mi++)
        #pragma unroll
        for (int ni = 0; ni < 2; ni++)
            acc[mi][ni] = (f32x4){0.f,0.f,0.f,0.f};

    for (int p = 0; p < 9; p++) {
        int kh = p / 3, kw = p - kh*3;
        const __hip_bfloat16* wp = wB + p*16384;
        int rbase0 = kh*66 + kw;
        #pragma unroll
        for (int ks = 0; ks < 4; ks++) {
            int ko = ks*32 + qq2*8;
            bf16x8 b0 = *(const bf16x8*)(wp + (n0 + lm)*128 + ko);
            bf16x8 b1 = *(const bf16x8*)(wp + (n0 + 16 + lm)*128 + ko);
            #pragma unroll
            for (int mi = 0; mi < 4; mi++) {
                int row = rbase0 + mi*16 + lm;
                bf16x8 a = *(const bf16x8*)&inrow[row*128 + (ko ^ ((row & 7) << 3))];
                acc[mi][0] = MFMA_BF16(a, b0, acc[mi][0]);
                acc[mi][1] = MFMA_BF16(a, b1, acc[mi][1]);
            }
        }
    }
    #pragma unroll
    for (int ni = 0; ni < 2; ni++) {
        int oc = n0 + ni*16 + lm;
        float bias = cb[oc];
        const float* rsp = (oc < 64) ? xr : xi;
        const float* rbase = &rsp[(bt*64 + (oc & 63))*HW + h*64];
        #pragma unroll
        for (int mi = 0; mi < 4; mi++) {
            #pragma unroll
            for (int r = 0; r < 4; r++) {
                int w = mi*16 + qq2*4 + r;
                x1[(size_t)(bt*HW + h*64 + w)*128 + oc] = acc[mi][ni][r] + bias + rbase[w];
            }
        }
    }
}

// ---------------- Stage 2: temporal via MFMA, f16 + hi/lo-split decode ----------------
// block = 128 thr / 2 waves, 4 pixels. A-tile 64 rows = (n_local,t), pitch 264:
// cols 0..127 = z then h_hi [re|im]; cols 128..255 = h_lo [re|im].
// GEMM1 (encode, K=128) -> in-fragment complex scan -> h hi/lo to tile -> GEMM2 (decode, K=256).
__global__ __launch_bounds__(128) void k_temporal_mfma(
    float* xio,
    const float* __restrict__ lw, const float* __restrict__ lb,
    const float* __restrict__ sbr, const float* __restrict__ sbi,
    const _Float16* __restrict__ Benc, const _Float16* __restrict__ BdecX,
    const float4* __restrict__ coefG, const float* __restrict__ nscG,
    const float* __restrict__ nzr, const float* __restrict__ nzi)
{
    __shared__ __align__(16) short At[64*TP];   // 33792 B
    int n0  = blockIdx.x * 4;
    int b   = n0 >> 12;
    int hw0 = n0 & 4095;
    int tid = threadIdx.x;

    // LN: 2 threads per row (row = n_local*16 + t), f16 into A-tile cols 0..127
    {
        int row = tid >> 1, half = tid & 1;
        int nl = row >> 4, t = row & 15;
        const float4* src = (const float4*)&xio[((size_t)((b*16 + t)*HW) + hw0 + nl)*128 + half*64];
        float4 v[16];
        float s = 0.f, s2 = 0.f;
        #pragma unroll
        for (int j = 0; j < 16; j++) {
            v[j] = src[j];
            s  += v[j].x + v[j].y + v[j].z + v[j].w;
            s2 += v[j].x*v[j].x + v[j].y*v[j].y + v[j].z*v[j].z + v[j].w*v[j].w;
        }
        s  += __shfl_xor(s, 1, 64);
        s2 += __shfl_xor(s2, 1, 64);
        float mu  = s * 0.0078125f;
        float var = s2 * 0.0078125f - mu*mu;
        float rsq = rsqrtf(var + 1e-5f);
        const float4* lw4 = (const float4*)(lw + half*64);
        const float4* lb4 = (const float4*)(lb + half*64);
        short* dstrow = &At[row*TP + half*64];
        #pragma unroll
        for (int j = 0; j < 16; j++) {
            float4 wv4 = lw4[j], bv = lb4[j];
            union { _Float16 h[4]; float2 f; } u;
            u.h[0] = (_Float16)((v[j].x - mu)*rsq*wv4.x + bv.x);
            u.h[1] = (_Float16)((v[j].y - mu)*rsq*wv4.y + bv.y);
            u.h[2] = (_Float16)((v[j].z - mu)*rsq*wv4.z + bv.z);
            u.h[3] = (_Float16)((v[j].w - mu)*rsq*wv4.w + bv.w);
            *(float2*)(dstrow + j*4) = u.f;
        }
    }
    __syncthreads();   // coef/LN cross-wave publish; tile rows are wave-private below

    int wv = tid >> 6, l = tid & 63, lm = l & 15, q = l >> 4;

    // GEMM1: u_pre = z @ Benc  (ni<4 = re cols, ni+4 = im cols)
    f32x4 acc[2][8];
    #pragma unroll
    for (int mi = 0; mi < 2; mi++)
        #pragma unroll
        for (int ni = 0; ni < 8; ni++)
            acc[mi][ni] = (f32x4){0.f,0.f,0.f,0.f};
    #pragma unroll
    for (int ks = 0; ks < 4; ks++) {
        int ko = ks*32 + q*8;
        f16x8 a0 = *(const f16x8*)&At[((2*wv+0)*16 + lm)*TP + ko];
        f16x8 a1 = *(const f16x8*)&At[((2*wv+1)*16 + lm)*TP + ko];
        #pragma unroll
        for (int ni = 0; ni < 8; ni++) {
            f16x8 bb = *(const f16x8*)(Benc + (ni*16 + lm)*128 + ko);
            acc[0][ni] = MFMA_F16(a0, bb, acc[0][ni]);
            acc[1][ni] = MFMA_F16(a1, bb, acc[1][ni]);
        }
    }

    // in-fragment complex scan (coef from global table); write h hi/lo into wave rows
    int btbase = b*16;
    #pragma unroll
    for (int ni = 0; ni < 4; ni++) {
        int e = ni*16 + lm;
        float br = sbr[e], bi = sbi[e];
        float4 cf[4]; float ns[4];
        #pragma unroll
        for (int r = 0; r < 4; r++) {
            int t = q*4 + r;
            cf[r] = coefG[(btbase + t)*64 + e];
            ns[r] = nscG[btbase + t];
        }
        #pragma unroll
        for (int mi = 0; mi < 2; mi++) {
            int nl = 2*wv + mi;
            int ng = n0 + nl;
            float nrv[4], niv[4];
            #pragma unroll
            for (int r = 0; r < 4; r++) {
                int off = (ng*16 + q*4 + r)*64 + e;
                nrv[r] = nzr[off];
                niv[r] = nzi[off];
            }
            float hr = 0.f, hi = 0.f, Apr = 1.f, Api = 0.f;
            float hrs[4], his[4], Aprs[4], Apis[4];
            #pragma unroll
            for (int r = 0; r < 4; r++) {
                float Sr = acc[mi][ni][r] + br;
                float Si = acc[mi][ni+4][r] + bi;
                float ur = Sr*cf[r].z - Si*cf[r].w + ns[r]*nrv[r];
                float ui = Sr*cf[r].w + Si*cf[r].z + ns[r]*niv[r];
                if (r == 0) { hr = ur; hi = ui; Apr = cf[0].x; Api = cf[0].y; }
                else {
                    float tr = cf[r].x*hr - cf[r].y*hi + ur;
                    float ti = cf[r].x*hi + cf[r].y*hr + ui;
                    hr = tr; hi = ti;
                    tr = cf[r].x*Apr - cf[r].y*Api;
                    ti = cf[r].x*Api + cf[r].y*Apr;
                    Apr = tr; Api = ti;
                }
                hrs[r] = hr; his[r] = hi; Aprs[r] = Apr; Apis[r] = Api;
            }
            // quad-prefix over segments (A,H): h_out = H + A*h_in
            float Ar = Apr, Ai = Api, Hr = hr, Hi = hi;
            #pragma unroll
            for (int off = 16; off <= 32; off <<= 1) {
                float pAr = __shfl_up(Ar, off, 64);
                float pAi = __shfl_up(Ai, off, 64);
                float pHr = __shfl_up(Hr, off, 64);
                float pHi = __shfl_up(Hi, off, 64);
                if (l >= off) {
                    Hr = Hr + Ar*pHr - Ai*pHi;
                    Hi = Hi + Ar*pHi + Ai*pHr;
                    float tAr = Ar*pAr - Ai*pAi;
                    float tAi = Ar*pAi + Ai*pAr;
                    Ar = tAr; Ai = tAi;
                }
            }
            float gr = __shfl_up(Hr, 16, 64);
            float gi = __shfl_up(Hi, 16, 64);
            if (q == 0) { gr = 0.f; gi = 0.f; }
            #pragma unroll
            for (int r = 0; r < 4; r++) {
                float fhr = hrs[r] + Aprs[r]*gr - Apis[r]*gi;
                float fhi = his[r] + Aprs[r]*gi + Apis[r]*gr;
                int row = nl*16 + q*4 + r;
                _Float16 hrh = (_Float16)fhr;
                _Float16 hih = (_Float16)fhi;
                *(_Float16*)&At[row*TP + e]        = hrh;
                *(_Float16*)&At[row*TP + 64 + e]   = hih;
                *(_Float16*)&At[row*TP + 128 + e]  = (_Float16)(fhr - (float)hrh);
                *(_Float16*)&At[row*TP + 192 + e]  = (_Float16)(fhi - (float)hih);
            }
        }
    }

    // GEMM2: drift = (h_hi + h_lo) @ BdecX  (K=256, duplicated weights)
    f32x4 acc2[2][4];
    #pragma unroll
    for (int mi = 0; mi < 2; mi++)
        #pragma unroll
        for (int ni = 0; ni < 4; ni++)
            acc2[mi][ni] = (f32x4){0.f,0.f,0.f,0.f};
    #pragma unroll
    for (int ks = 0; ks < 8; ks++) {
        int ko = ks*32 + q*8;
        f16x8 a0 = *(const f16x8*)&At[((2*wv+0)*16 + lm)*TP + ko];
        f16x8 a1 = *(const f16x8*)&At[((2*wv+1)*16 + lm)*TP + ko];
        #pragma unroll
        for (int ni = 0; ni < 4; ni++) {
            f16x8 bb = *(const f16x8*)(BdecX + (ni*16 + lm)*256 + ko);
            acc2[0][ni] = MFMA_F16(a0, bb, acc2[0][ni]);
            acc2[1][ni] = MFMA_F16(a1, bb, acc2[1][ni]);
        }
    }

    // epilogue: xio.re += drift (in place, re-half only)
    #pragma unroll
    for (int mi = 0; mi < 2; mi++) {
        int nl = 2*wv + mi;
        #pragma unroll
        for (int ni = 0; ni < 4; ni++) {
            int d = ni*16 + lm;
            #pragma unroll
            for (int r = 0; r < 4; r++) {
                int t = q*4 + r;
                size_t idx = ((size_t)((b*16 + t)*HW) + hw0 + nl)*128 + d;
                xio[idx] = xio[idx] + acc2[mi][ni][r];
            }
        }
    }
}

// ---------------- Stage 3: MoE FFN via MFMA (measured-best 114 us structure) ----
// 256 thr / 64 tokens / 35.8 KB LDS. Column-split: wave owns a 32-col weight strip.
__global__ __launch_bounds__(256) void k_moe_mfma(
    const float* __restrict__ xio,
    float* __restrict__ outp,
    const __hip_bfloat16* __restrict__ rwB, const float* __restrict__ rb,
    const __hip_bfloat16* __restrict__ w1b, const float* __restrict__ b1,
    const __hip_bfloat16* __restrict__ w2b, const float* __restrict__ b2)
{
    __shared__ __align__(16) short smem[2*64*136];   // tokA | hidA; reused as fp32 tile 64x129
    __shared__ float gates[256];
    short* tokA = smem;
    short* hidA = smem + 64*136;
    float* tile = (float*)smem;
    int tok0 = blockIdx.x * 64;
    int tid = threadIdx.x;
    for (int lsd = tid; lsd < 2048; lsd += 256) {
        int t = lsd >> 5, j = lsd & 31;
        float4 v = *(const float4*)&xio[(size_t)(tok0 + t)*128 + j*4];
        union { __hip_bfloat16 h[4]; float2 f; } u;
        u.h[0] = __float2bfloat16(v.x);
        u.h[1] = __float2bfloat16(v.y);
        u.h[2] = __float2bfloat16(v.z);
        u.h[3] = __float2bfloat16(v.w);
        *(float2*)&tokA[t*136 + j*4] = u.f;
    }
    __syncthreads();

    int wv = tid >> 6, l = tid & 63, lm = l & 15, q = l >> 4;
    int n0 = wv * 32;

    // Router via MFMA: wave wv computes logits for token rows [n0, n0+32).
    // gates published to other waves by the post-GELU barrier of expert 0.
    {
        f32x4 racc[2];
        racc[0] = (f32x4){0.f,0.f,0.f,0.f};
        racc[1] = (f32x4){0.f,0.f,0.f,0.f};
        #pragma unroll
        for (int ks = 0; ks < 4; ks++) {
            int ko = ks*32 + q*8;
            bf16x8 bb = *(const bf16x8*)(rwB + lm*128 + ko);
            bf16x8 a0 = *(const bf16x8*)&tokA[(n0 + lm)*136 + ko];
            bf16x8 a1 = *(const bf16x8*)&tokA[(n0 + 16 + lm)*136 + ko];
            racc[0] = MFMA_BF16(a0, bb, racc[0]);
            racc[1] = MFMA_BF16(a1, bb, racc[1]);
        }
        float rb_l = rb[lm & 3];
        #pragma unroll
        for (int mi = 0; mi < 2; mi++) {
            #pragma unroll
            for (int r = 0; r < 4; r++) {
                float g = racc[mi][r] + rb_l;
                float mx = fmaxf(g, __shfl_xor(g, 1, 64));
                mx = fmaxf(mx, __shfl_xor(mx, 2, 64));
                float ev = __expf(g - mx);
                float sv = ev + __shfl_xor(ev, 1, 64);
                sv += __shfl_xor(sv, 2, 64);
                if (lm < 4)
                    gates[(n0 + mi*16 + q*4 + r)*4 + lm] = ev * __builtin_amdgcn_rcpf(sv);
            }
        }
    }

    f32x4 outa[4][2];
    #pragma unroll
    for (int mi = 0; mi < 4; mi++)
        #pragma unroll
        for (int ni = 0; ni < 2; ni++)
            outa[mi][ni] = (f32x4){0.f,0.f,0.f,0.f};

    for (int e = 0; e < 4; e++) {
        // GEMM1: hid[all 64 rows][n0..n0+32) = tok @ w1[e] strip  (reads tokA only)
        f32x4 acc1[4][2];
        #pragma unroll
        for (int mi = 0; mi < 4; mi++)
            #pragma unroll
            for (int ni = 0; ni < 2; ni++)
                acc1[mi][ni] = (f32x4){0.f,0.f,0.f,0.f};
        const __hip_bfloat16* wp1 = w1b + e*16384;
        #pragma unroll
        for (int ks = 0; ks < 4; ks++) {
            int ko = ks*32 + q*8;
            bf16x8 b0  = *(const bf16x8*)(wp1 + (n0 + lm)*128 + ko);
            bf16x8 b1v = *(const bf16x8*)(wp1 + (n0 + 16 + lm)*128 + ko);
            #pragma unroll
            for (int mi = 0; mi < 4; mi++) {
                bf16x8 a = *(const bf16x8*)&tokA[(mi*16 + lm)*136 + ko];
                acc1[mi][0] = MFMA_BF16(a, b0,  acc1[mi][0]);
                acc1[mi][1] = MFMA_BF16(a, b1v, acc1[mi][1]);
            }
        }
        // GELU -> hidA own cols (writes fenced vs GEMM2(e-1) by loop-end barrier)
        #pragma unroll
        for (int ni = 0; ni < 2; ni++) {
            int hcol = n0 + ni*16 + lm;
            float bb = b1[e*128 + hcol];
            #pragma unroll
            for (int mi = 0; mi < 4; mi++) {
                #pragma unroll
                for (int r = 0; r < 4; r++) {
                    float hv = gelu_f(acc1[mi][ni][r] + bb);
                    int m = mi*16 + q*4 + r;
                    *(__hip_bfloat16*)&hidA[m*136 + hcol] = __float2bfloat16(hv);
                }
            }
        }
        __syncthreads();   // publish hidA (and gates on e=0)
        // GEMM2: delta[all rows][n0..n0+32) = hid @ w2[e] strip (contracts all 128 h-cols)
        f32x4 acc2[4][2];
        #pragma unroll
        for (int mi = 0; mi < 4; mi++)
            #pragma unroll
            for (int ni = 0; ni < 2; ni++)
                acc2[mi][ni] = (f32x4){0.f,0.f,0.f,0.f};
        const __hip_bfloat16* wp2 = w2b + e*16384;
        #pragma unroll
        for (int ks = 0; ks < 4; ks++) {
            int ko = ks*32 + q*8;
            bf16x8 b0  = *(const bf16x8*)(wp2 + (n0 + lm)*128 + ko);
            bf16x8 b1v = *(const bf16x8*)(wp2 + (n0 + 16 + lm)*128 + ko);
            #pragma unroll
            for (int mi = 0; mi < 4; mi++) {
                bf16x8 a = *(const bf16x8*)&hidA[(mi*16 + lm)*136 + ko];
                acc2[mi][0] = MFMA_BF16(a, b0,  acc2[mi][0]);
                acc2[mi][1] = MFMA_BF16(a, b1v, acc2[mi][1]);
            }
        }
        #pragma unroll
        for (int ni = 0; ni < 2; ni++) {
            int ocol = n0 + ni*16 + lm;
            float bb = b2[e*128 + ocol];
            #pragma unroll
            for (int mi = 0; mi < 4; mi++) {
                #pragma unroll
                for (int r = 0; r < 4; r++) {
                    int m = mi*16 + q*4 + r;
                    float g = gates[m*4 + e];
                    outa[mi][ni][r] += g * (acc2[mi][ni][r] + bb);
                }
            }
        }
        __syncthreads();   // hidA readers done before next expert's GELU overwrites
    }

    // final = residual + delta -> LDS tile (pitch 129) -> native-layout store
    #pragma unroll
    for (int ni = 0; ni < 2; ni++) {
        int col = n0 + ni*16 + lm;
        #pragma unroll
        for (int mi = 0; mi < 4; mi++) {
            #pragma unroll
            for (int r = 0; r < 4; r++) {
                int m = mi*16 + q*4 + r;
                tile[m*129 + col] = xio[(size_t)(tok0 + m)*128 + col] + outa[mi][ni][r];
            }
        }
    }
    __syncthreads();
    int bt = tok0 >> 12;
    int hw0 = tok0 & 4095;
    for (int lid = tid; lid < 8192; lid += 256) {
        int c = lid >> 6, m = lid & 63;
        int p = c >> 6, d = c & 63;
        outp[((size_t)((p*32 + bt)*64 + d))*HW + hw0 + m] = tile[m*129 + c];
    }
}

extern "C" void kernel_launch(void* const* d_in, const int* in_sizes, int n_in,
                              void* d_out, int out_size, void* d_ws, size_t ws_size,
                              hipStream_t stream)
{
    const float* x_real = (const float*)d_in[0];
    const float* x_imag = (const float*)d_in[1];
    const float* dt     = (const float*)d_in[2];
    const float* nzr    = (const float*)d_in[3];
    const float* nzi    = (const float*)d_in[4];
    const float* ln_s_w = (const float*)d_in[5];
    const float* ln_s_b = (const float*)d_in[6];
    const float* conv_w = (const float*)d_in[7];
    const float* conv_b = (const float*)d_in[8];
    const float* ln_t_w = (const float*)d_in[9];
    const float* ln_t_b = (const float*)d_in[10];
    const float* lam_re = (const float*)d_in[11];
    const float* lam_im = (const float*)d_in[12];
    const float* sbr    = (const float*)d_in[13];
    const float* sbi    = (const float*)d_in[14];
    const float* enc_re = (const float*)d_in[15];
    const float* enc_im = (const float*)d_in[16];
    const float* dec_re = (const float*)d_in[17];
    const float* dec_im = (const float*)d_in[18];
    const float* rw     = (const float*)d_in[19];
    const float* rb     = (const float*)d_in[20];
    const float* w1     = (const float*)d_in[21];
    const float* b1     = (const float*)d_in[22];
    const float* w2     = (const float*)d_in[23];
    const float* b2     = (const float*)d_in[24];

    char* ws = (char*)d_ws;
    float* bufA = (float*)ws;                                              // 64 MiB fp32 layout-A
    __hip_bfloat16* wBc  = (__hip_bfloat16*)(ws + (size_t)96*1024*1024);   // conv weights [9][oc][ic]
    __hip_bfloat16* w1b  = wBc + 9*16384;
    __hip_bfloat16* w2b  = w1b + 4*16384;
    _Float16* Benc  = (_Float16*)(w2b + 4*16384);                          // [128][128] f16
    _Float16* BdecX = Benc + 16384;                                        // [64][256] f16
    float4* coefG = (float4*)(BdecX + 16384);                              // [2048]
    float* nscG   = (float*)(coefG + 2048);                                // [32]
    __hip_bfloat16* rwB = (__hip_bfloat16*)(nscG + 32);                    // [16][128] bf16 router
    float* outp = (float*)d_out;

    k_prep_t  <<<dim3(9,16), 256, 0, stream>>>(conv_w, wBc);
    k_prep_t  <<<dim3(4,16), 256, 0, stream>>>(w1, w1b);
    k_prep_t  <<<dim3(4,16), 256, 0, stream>>>(w2, w2b);
    k_prep_enc<<<64,         256, 0, stream>>>(enc_re, enc_im, dec_re, dec_im,
                                               dt, lam_re, lam_im, rw,
                                               Benc, BdecX, coefG, nscG, rwB);

    k_conv_mfma    <<<dim3(32,64), 256, 0, stream>>>(x_real, x_imag, ln_s_w, ln_s_b,
                                                     wBc, conv_b, bufA);
    k_temporal_mfma<<<2048,        128, 0, stream>>>(bufA, ln_t_w, ln_t_b, sbr, sbi,
                                                     Benc, BdecX, coefG, nscG, nzr, nzi);
    k_moe_mfma     <<<2048,        256, 0, stream>>>(bufA, outp, rwB, rb, w1b, b1, w2b, b2);
}